// Round 1
// baseline (3998.992 us; speedup 1.0000x reference)
//
#include <hip/hip_runtime.h>
#include <math.h>

#define D_MODEL 1024
#define D_INNER 2048
#define D_STATE 16
#define DT_RANK 64
#define BATCH 4
#define SEQLEN 2048
#define NROWS (BATCH*SEQLEN)   // 8192

// ---------------------------------------------------------------------------
// Generic fp32 GEMM:  C[M,N] = A[M,K] * W[N,K]^T   (both K-contiguous)
// 256 threads; tile BM=16*TM x BN=16*TN; K-step BK.
// EPI: 0 = plain store (ldc=N)
//      1 = split store: col < D_INNER -> C0 (x), else -> C1 (z), ldc=D_INNER
//      2 = softplus(acc + bias[col]) store (ldc=N)   [dt path]
// ---------------------------------------------------------------------------
template<int TM, int TN, int BK, int EPI>
__global__ __launch_bounds__(256) void gemm_bt(
    const float* __restrict__ A, const float* __restrict__ W,
    float* C0, float* C1, const float* __restrict__ bias,
    int M, int N, int K, int lda)
{
  constexpr int BM = 16 * TM, BN = 16 * TN;
  __shared__ float As[BK][BM + 4];
  __shared__ float Ws[BK][BN + 4];

  const int tid = threadIdx.x;
  const int tx = tid & 15, ty = tid >> 4;
  const int row0 = blockIdx.y * BM, col0 = blockIdx.x * BN;

  float acc[TM][TN];
#pragma unroll
  for (int i = 0; i < TM; i++)
#pragma unroll
    for (int j = 0; j < TN; j++) acc[i][j] = 0.f;

  for (int k0 = 0; k0 < K; k0 += BK) {
    // stage A tile (BM x BK) transposed -> As[k][m]
    for (int i = tid; i < BM * BK; i += 256) {
      int m = i / BK, kk = i % BK;
      As[kk][m] = A[(size_t)(row0 + m) * lda + k0 + kk];
    }
    // stage W tile (BN x BK) transposed -> Ws[k][n]
    for (int i = tid; i < BN * BK; i += 256) {
      int nn = i / BK, kk = i % BK;
      Ws[kk][nn] = W[(size_t)(col0 + nn) * K + k0 + kk];
    }
    __syncthreads();

#pragma unroll
    for (int kk = 0; kk < BK; kk++) {
      float a[TM], bb[TN];
#pragma unroll
      for (int i = 0; i < TM; i++) a[i] = As[kk][ty * TM + i];
#pragma unroll
      for (int j = 0; j < TN; j++) bb[j] = Ws[kk][tx * TN + j];
#pragma unroll
      for (int i = 0; i < TM; i++)
#pragma unroll
        for (int j = 0; j < TN; j++)
          acc[i][j] = fmaf(a[i], bb[j], acc[i][j]);
    }
    __syncthreads();
  }

#pragma unroll
  for (int i = 0; i < TM; i++) {
    const int row = row0 + ty * TM + i;
#pragma unroll
    for (int j = 0; j < TN; j++) {
      const int col = col0 + tx * TN + j;
      float v = acc[i][j];
      if (EPI == 0) {
        C0[(size_t)row * N + col] = v;
      } else if (EPI == 1) {
        if (col < D_INNER) C0[(size_t)row * D_INNER + col] = v;
        else               C1[(size_t)row * D_INNER + col - D_INNER] = v;
      } else {
        float t = v + bias[col];
        float sp = (t > 20.f) ? t : log1pf(expf(t));
        C0[(size_t)row * N + col] = sp;
      }
    }
  }
}

// ---------------------------------------------------------------------------
// Causal depthwise conv1d (K=4) + bias + SiLU.  x,xs layout: (B,L,D) d-contig.
// ---------------------------------------------------------------------------
__global__ __launch_bounds__(256) void conv_silu(
    const float* __restrict__ x, const float* __restrict__ w,
    const float* __restrict__ b, float* __restrict__ xs)
{
  const int idx = blockIdx.x * 256 + threadIdx.x;  // = (b*L + l)*D + d
  const int d = idx & (D_INNER - 1);
  const int bl = idx / D_INNER;
  const int l = bl & (SEQLEN - 1);
  float acc = b[d];
#pragma unroll
  for (int k = 0; k < 4; k++) {
    int ls = l + k - 3;
    if (ls >= 0) acc = fmaf(x[(size_t)(bl + k - 3) * D_INNER + d], w[d * 4 + k], acc);
  }
  xs[idx] = acc / (1.f + expf(-acc));   // SiLU
}

// ---------------------------------------------------------------------------
// Selective scan. 16 lanes (n=0..15) per (b,d) channel; 16 channels / block.
// Fuses the D-skip and z-gating epilogue. y is written over the dt buffer
// (same slot this thread-group just read -- safe within the wave).
// ---------------------------------------------------------------------------
__global__ __launch_bounds__(256) void scan_kernel(
    const float* dtb, const float* __restrict__ xs,
    const float* __restrict__ z, const float* __restrict__ xdbl,
    const float* __restrict__ A_log, const float* __restrict__ Dp,
    float* y)
{
  const int gid = blockIdx.x * 256 + threadIdx.x;
  const int n = gid & 15;
  const int ch = gid >> 4;              // b*D_INNER + d
  const int d = ch & (D_INNER - 1);
  const int b = ch >> 11;               // / D_INNER

  const float Aval = -expf(A_log[d * D_STATE + n]);
  const float Dval = Dp[d];
  float state = 0.f;

#pragma unroll 2
  for (int l = 0; l < SEQLEN; l++) {
    const int rowi = b * SEQLEN + l;
    const size_t ix = (size_t)rowi * D_INNER + d;
    const float dtv = dtb[ix];
    const float xv  = xs[ix];
    const float zv  = z[ix];
    const float Bv  = xdbl[(size_t)rowi * 96 + 64 + n];
    const float Cv  = xdbl[(size_t)rowi * 96 + 80 + n];

    const float dA = expf(dtv * Aval);
    state = fmaf(state, dA, dtv * xv * Bv);

    float p = state * Cv;
    p += __shfl_xor(p, 8, 16);
    p += __shfl_xor(p, 4, 16);
    p += __shfl_xor(p, 2, 16);
    p += __shfl_xor(p, 1, 16);

    if (n == 0) {
      float yv = fmaf(xv, Dval, p);
      float g = zv / (1.f + expf(-zv));
      y[ix] = yv * g;
    }
  }
}

// ---------------------------------------------------------------------------
extern "C" void kernel_launch(void* const* d_in, const int* in_sizes, int n_in,
                              void* d_out, int out_size, void* d_ws, size_t ws_size,
                              hipStream_t stream)
{
  const float* hidden     = (const float*)d_in[0];
  const float* in_proj_w  = (const float*)d_in[1];
  const float* conv_w     = (const float*)d_in[2];
  const float* conv_b     = (const float*)d_in[3];
  const float* x_proj_w   = (const float*)d_in[4];
  const float* dt_proj_w  = (const float*)d_in[5];
  const float* dt_proj_b  = (const float*)d_in[6];
  const float* A_log      = (const float*)d_in[7];
  const float* Dparam     = (const float*)d_in[8];
  const float* out_proj_w = (const float*)d_in[9];
  float* out = (float*)d_out;

  const size_t NE = (size_t)NROWS * D_INNER;   // 16.78M floats
  float* xbuf  = (float*)d_ws;      // x -> dt -> y  (reused)
  float* zbuf  = xbuf + NE;
  float* xsbuf = zbuf + NE;
  float* xdbl  = xsbuf + NE;        // NROWS * 96

  // 1) in_proj: (8192x1024)x(4096x1024)^T -> split x | z
  gemm_bt<8, 8, 16, 1><<<dim3((2 * D_INNER) / 128, NROWS / 128), 256, 0, stream>>>(
      hidden, in_proj_w, xbuf, zbuf, nullptr, NROWS, 2 * D_INNER, D_MODEL, D_MODEL);

  // 2) causal depthwise conv + SiLU
  conv_silu<<<(NROWS * D_INNER) / 256, 256, 0, stream>>>(xbuf, conv_w, conv_b, xsbuf);

  // 3) x_proj: (8192x2048)x(96x2048)^T -> x_dbl (dt_raw|B|C)
  gemm_bt<2, 6, 16, 0><<<dim3(1, NROWS / 32), 256, 0, stream>>>(
      xsbuf, x_proj_w, xdbl, xdbl, nullptr, NROWS, 96, D_INNER, D_INNER);

  // 4) dt_proj + softplus: (8192x64 of x_dbl)x(2048x64)^T -> dt (into xbuf)
  gemm_bt<8, 8, 16, 2><<<dim3(D_INNER / 128, NROWS / 128), 256, 0, stream>>>(
      xdbl, dt_proj_w, xbuf, xbuf, dt_proj_b, NROWS, D_INNER, DT_RANK, 96);

  // 5) selective scan + D-skip + z-gating (y overwrites dt in xbuf)
  scan_kernel<<<(BATCH * D_INNER) / 16, 256, 0, stream>>>(
      xbuf, xsbuf, zbuf, xdbl, A_log, Dparam, xbuf);

  // 6) out_proj: (8192x2048)x(1024x2048)^T -> out
  gemm_bt<8, 8, 16, 0><<<dim3(D_MODEL / 128, NROWS / 128), 256, 0, stream>>>(
      xbuf, out_proj_w, out, out, nullptr, NROWS, D_MODEL, D_INNER, D_INNER);
}

// Round 2
// 2555.974 us; speedup vs baseline: 1.5646x; 1.5646x over previous
//
#include <hip/hip_runtime.h>
#include <math.h>

#define D_MODEL 1024
#define D_INNER 2048
#define D_STATE 16
#define DT_RANK 64
#define BATCH 4
#define SEQLEN 2048
#define NROWS (BATCH*SEQLEN)   // 8192

typedef __attribute__((ext_vector_type(8))) short short8;
typedef __attribute__((ext_vector_type(4))) float f32x4;

__device__ __forceinline__ unsigned short bf16rn(float f) {
  unsigned int u = __float_as_uint(f);
  unsigned int r = (u + 0x7FFFu + ((u >> 16) & 1u)) >> 16;
  return (unsigned short)r;
}
__device__ __forceinline__ float bf16tof(unsigned short h) {
  return __uint_as_float(((unsigned int)h) << 16);
}

// ---------------------------------------------------------------------------
// Split-bf16 MFMA GEMM:  C[M,N] = A[M,K] * W[N,K]^T  (both K-contiguous).
// fp32 operands split into hi+lo bf16; acc += hi*hi + hi*lo + lo*hi  (3 MFMA)
// => ~fp32 accuracy at MFMA rate/3.
// 128x128 tile, BK=32, 256 thr = 4 waves (2x2), 16x16x32 bf16 MFMA, 4x4 frags.
// EPI: 0 = plain store (ldc=N); 1 = split x|z at D_INNER (ldc=D_INNER)
// ---------------------------------------------------------------------------
template<int EPI>
__global__ __launch_bounds__(256) void gemm_mfma(
    const float* __restrict__ A, const float* __restrict__ W,
    float* __restrict__ C0, float* __restrict__ C1,
    int M, int N, int K)
{
  // [kblk][row][8] ushort: fragment = 8 contiguous bf16 at 16B-aligned addr
  __shared__ __align__(16) unsigned short As_hi[4][128][8];
  __shared__ __align__(16) unsigned short As_lo[4][128][8];
  __shared__ __align__(16) unsigned short Ws_hi[4][128][8];
  __shared__ __align__(16) unsigned short Ws_lo[4][128][8];

  const int tid = threadIdx.x;
  const int lane = tid & 63, wid = tid >> 6;
  const int wy = wid >> 1, wx = wid & 1;       // wave quadrant (2x2 of 64x64)
  const int lr = lane & 15, lk = lane >> 4;    // frag row/col, kblk
  const int row0 = blockIdx.y * 128, col0 = blockIdx.x * 128;

  const int qr = tid >> 3;      // 0..31 : staging row group
  const int qc = tid & 7;       // 0..7  : float4 within row (32 floats)
  const float* Ag = A + (size_t)(row0 + qr) * K + qc * 4;
  const float* Wg = W + (size_t)(col0 + qr) * K + qc * 4;

  f32x4 acc[4][4];
#pragma unroll
  for (int i = 0; i < 4; i++)
#pragma unroll
    for (int j = 0; j < 4; j++) acc[i][j] = (f32x4){0.f, 0.f, 0.f, 0.f};

  float4 ar[4], wr_[4];

#define LOADT(K0)                                                     \
  {                                                                   \
    _Pragma("unroll")                                                 \
    for (int i = 0; i < 4; i++) {                                     \
      ar[i]  = *(const float4*)(Ag + (size_t)(32 * i) * K + (K0));    \
      wr_[i] = *(const float4*)(Wg + (size_t)(32 * i) * K + (K0));    \
    }                                                                 \
  }

  LOADT(0);
  const int KT = K >> 5;
  const int kb = qc >> 1, off = (qc & 1) * 4;

  for (int kt = 0; kt < KT; kt++) {
    // convert + stage current tile
#pragma unroll
    for (int i = 0; i < 4; i++) {
      const int row = qr + 32 * i;
      {
        float4 v = ar[i];
        unsigned short h0 = bf16rn(v.x), h1 = bf16rn(v.y), h2 = bf16rn(v.z), h3 = bf16rn(v.w);
        unsigned short l0 = bf16rn(v.x - bf16tof(h0)), l1 = bf16rn(v.y - bf16tof(h1));
        unsigned short l2 = bf16rn(v.z - bf16tof(h2)), l3 = bf16rn(v.w - bf16tof(h3));
        *(uint2*)&As_hi[kb][row][off] = make_uint2(h0 | ((unsigned)h1 << 16), h2 | ((unsigned)h3 << 16));
        *(uint2*)&As_lo[kb][row][off] = make_uint2(l0 | ((unsigned)l1 << 16), l2 | ((unsigned)l3 << 16));
      }
      {
        float4 v = wr_[i];
        unsigned short h0 = bf16rn(v.x), h1 = bf16rn(v.y), h2 = bf16rn(v.z), h3 = bf16rn(v.w);
        unsigned short l0 = bf16rn(v.x - bf16tof(h0)), l1 = bf16rn(v.y - bf16tof(h1));
        unsigned short l2 = bf16rn(v.z - bf16tof(h2)), l3 = bf16rn(v.w - bf16tof(h3));
        *(uint2*)&Ws_hi[kb][row][off] = make_uint2(h0 | ((unsigned)h1 << 16), h2 | ((unsigned)h3 << 16));
        *(uint2*)&Ws_lo[kb][row][off] = make_uint2(l0 | ((unsigned)l1 << 16), l2 | ((unsigned)l3 << 16));
      }
    }
    // prefetch next tile into regs (in flight across the MFMA phase)
    if (kt + 1 < KT) LOADT((kt + 1) << 5);
    __syncthreads();

    short8 ah[4], al[4];
#pragma unroll
    for (int mi = 0; mi < 4; mi++) {
      ah[mi] = *(const short8*)&As_hi[lk][wy * 64 + mi * 16 + lr][0];
      al[mi] = *(const short8*)&As_lo[lk][wy * 64 + mi * 16 + lr][0];
    }
#pragma unroll
    for (int ni = 0; ni < 4; ni++) {
      const short8 bh = *(const short8*)&Ws_hi[lk][wx * 64 + ni * 16 + lr][0];
      const short8 bl = *(const short8*)&Ws_lo[lk][wx * 64 + ni * 16 + lr][0];
#pragma unroll
      for (int mi = 0; mi < 4; mi++) {
        acc[mi][ni] = __builtin_amdgcn_mfma_f32_16x16x32_bf16(ah[mi], bh, acc[mi][ni], 0, 0, 0);
        acc[mi][ni] = __builtin_amdgcn_mfma_f32_16x16x32_bf16(ah[mi], bl, acc[mi][ni], 0, 0, 0);
        acc[mi][ni] = __builtin_amdgcn_mfma_f32_16x16x32_bf16(al[mi], bh, acc[mi][ni], 0, 0, 0);
      }
    }
    __syncthreads();
  }
#undef LOADT

#pragma unroll
  for (int mi = 0; mi < 4; mi++)
#pragma unroll
    for (int ni = 0; ni < 4; ni++)
#pragma unroll
      for (int j = 0; j < 4; j++) {
        const int row = row0 + wy * 64 + mi * 16 + lk * 4 + j;
        const int col = col0 + wx * 64 + ni * 16 + lr;
        const float v = acc[mi][ni][j];
        if (EPI == 0) {
          C0[(size_t)row * N + col] = v;
        } else {
          if (col < D_INNER) C0[(size_t)row * D_INNER + col] = v;
          else               C1[(size_t)row * D_INNER + col - D_INNER] = v;
        }
      }
}

// ---------------------------------------------------------------------------
// fp32 VALU GEMM (kept for the small x_proj / dt_proj matmuls)
// EPI: 0 plain, 2 softplus(acc+bias)
// ---------------------------------------------------------------------------
template<int TM, int TN, int BK, int EPI>
__global__ __launch_bounds__(256) void gemm_bt(
    const float* __restrict__ A, const float* __restrict__ W,
    float* C0, const float* __restrict__ bias,
    int M, int N, int K, int lda)
{
  constexpr int BM = 16 * TM, BN = 16 * TN;
  __shared__ float As[BK][BM + 4];
  __shared__ float Ws[BK][BN + 4];

  const int tid = threadIdx.x;
  const int tx = tid & 15, ty = tid >> 4;
  const int row0 = blockIdx.y * BM, col0 = blockIdx.x * BN;

  float acc[TM][TN];
#pragma unroll
  for (int i = 0; i < TM; i++)
#pragma unroll
    for (int j = 0; j < TN; j++) acc[i][j] = 0.f;

  for (int k0 = 0; k0 < K; k0 += BK) {
    for (int i = tid; i < BM * BK; i += 256) {
      int m = i / BK, kk = i % BK;
      As[kk][m] = A[(size_t)(row0 + m) * lda + k0 + kk];
    }
    for (int i = tid; i < BN * BK; i += 256) {
      int nn = i / BK, kk = i % BK;
      Ws[kk][nn] = W[(size_t)(col0 + nn) * K + k0 + kk];
    }
    __syncthreads();
#pragma unroll
    for (int kk = 0; kk < BK; kk++) {
      float a[TM], bb[TN];
#pragma unroll
      for (int i = 0; i < TM; i++) a[i] = As[kk][ty * TM + i];
#pragma unroll
      for (int j = 0; j < TN; j++) bb[j] = Ws[kk][tx * TN + j];
#pragma unroll
      for (int i = 0; i < TM; i++)
#pragma unroll
        for (int j = 0; j < TN; j++)
          acc[i][j] = fmaf(a[i], bb[j], acc[i][j]);
    }
    __syncthreads();
  }

#pragma unroll
  for (int i = 0; i < TM; i++) {
    const int row = row0 + ty * TM + i;
#pragma unroll
    for (int j = 0; j < TN; j++) {
      const int col = col0 + tx * TN + j;
      float v = acc[i][j];
      if (EPI == 0) {
        C0[(size_t)row * N + col] = v;
      } else {
        float t = v + bias[col];
        float sp = (t > 20.f) ? t : log1pf(expf(t));
        C0[(size_t)row * N + col] = sp;
      }
    }
  }
}

// ---------------------------------------------------------------------------
// Causal depthwise conv1d (K=4) + bias + SiLU.  (B,L,D) d-contig.
// ---------------------------------------------------------------------------
__global__ __launch_bounds__(256) void conv_silu(
    const float* __restrict__ x, const float* __restrict__ w,
    const float* __restrict__ b, float* __restrict__ xs)
{
  const int idx = blockIdx.x * 256 + threadIdx.x;
  const int d = idx & (D_INNER - 1);
  const int bl = idx / D_INNER;
  const int l = bl & (SEQLEN - 1);
  float acc = b[d];
#pragma unroll
  for (int k = 0; k < 4; k++) {
    int ls = l + k - 3;
    if (ls >= 0) acc = fmaf(x[(size_t)(bl + k - 3) * D_INNER + d], w[d * 4 + k], acc);
  }
  xs[idx] = acc / (1.f + expf(-acc));
}

// ---------------------------------------------------------------------------
// Selective scan (unchanged this round; Round-3 target).
// ---------------------------------------------------------------------------
__global__ __launch_bounds__(256) void scan_kernel(
    const float* dtb, const float* __restrict__ xs,
    const float* __restrict__ z, const float* __restrict__ xdbl,
    const float* __restrict__ A_log, const float* __restrict__ Dp,
    float* y)
{
  const int gid = blockIdx.x * 256 + threadIdx.x;
  const int n = gid & 15;
  const int ch = gid >> 4;
  const int d = ch & (D_INNER - 1);
  const int b = ch >> 11;

  const float Aval = -expf(A_log[d * D_STATE + n]);
  const float Dval = Dp[d];
  float state = 0.f;

#pragma unroll 2
  for (int l = 0; l < SEQLEN; l++) {
    const int rowi = b * SEQLEN + l;
    const size_t ix = (size_t)rowi * D_INNER + d;
    const float dtv = dtb[ix];
    const float xv  = xs[ix];
    const float zv  = z[ix];
    const float Bv  = xdbl[(size_t)rowi * 96 + 64 + n];
    const float Cv  = xdbl[(size_t)rowi * 96 + 80 + n];

    const float dA = expf(dtv * Aval);
    state = fmaf(state, dA, dtv * xv * Bv);

    float p = state * Cv;
    p += __shfl_xor(p, 8, 16);
    p += __shfl_xor(p, 4, 16);
    p += __shfl_xor(p, 2, 16);
    p += __shfl_xor(p, 1, 16);

    if (n == 0) {
      float yv = fmaf(xv, Dval, p);
      float g = zv / (1.f + expf(-zv));
      y[ix] = yv * g;
    }
  }
}

// ---------------------------------------------------------------------------
extern "C" void kernel_launch(void* const* d_in, const int* in_sizes, int n_in,
                              void* d_out, int out_size, void* d_ws, size_t ws_size,
                              hipStream_t stream)
{
  const float* hidden     = (const float*)d_in[0];
  const float* in_proj_w  = (const float*)d_in[1];
  const float* conv_w     = (const float*)d_in[2];
  const float* conv_b     = (const float*)d_in[3];
  const float* x_proj_w   = (const float*)d_in[4];
  const float* dt_proj_w  = (const float*)d_in[5];
  const float* dt_proj_b  = (const float*)d_in[6];
  const float* A_log      = (const float*)d_in[7];
  const float* Dparam     = (const float*)d_in[8];
  const float* out_proj_w = (const float*)d_in[9];
  float* out = (float*)d_out;

  const size_t NE = (size_t)NROWS * D_INNER;
  float* xbuf  = (float*)d_ws;      // x -> dt -> y (reused)
  float* zbuf  = xbuf + NE;
  float* xsbuf = zbuf + NE;
  float* xdbl  = xsbuf + NE;        // NROWS * 96

  // 1) in_proj (split-bf16 MFMA): (8192x1024)x(4096x1024)^T -> x | z
  gemm_mfma<1><<<dim3((2 * D_INNER) / 128, NROWS / 128), 256, 0, stream>>>(
      hidden, in_proj_w, xbuf, zbuf, NROWS, 2 * D_INNER, D_MODEL);

  // 2) causal depthwise conv + SiLU
  conv_silu<<<(NROWS * D_INNER) / 256, 256, 0, stream>>>(xbuf, conv_w, conv_b, xsbuf);

  // 3) x_proj: (8192x2048)x(96x2048)^T -> x_dbl
  gemm_bt<2, 6, 16, 0><<<dim3(1, NROWS / 32), 256, 0, stream>>>(
      xsbuf, x_proj_w, xdbl, nullptr, NROWS, 96, D_INNER, D_INNER);

  // 4) dt_proj + softplus -> dt (into xbuf)
  gemm_bt<8, 8, 16, 2><<<dim3(D_INNER / 128, NROWS / 128), 256, 0, stream>>>(
      xdbl, dt_proj_w, xbuf, dt_proj_b, NROWS, D_INNER, DT_RANK, 96);

  // 5) selective scan + D-skip + z-gating (y overwrites dt in xbuf)
  scan_kernel<<<(BATCH * D_INNER) / 16, 256, 0, stream>>>(
      xbuf, xsbuf, zbuf, xdbl, A_log, Dparam, xbuf);

  // 6) out_proj (split-bf16 MFMA): (8192x2048)x(1024x2048)^T -> out
  gemm_mfma<0><<<dim3(D_MODEL / 128, NROWS / 128), 256, 0, stream>>>(
      xbuf, out_proj_w, out, nullptr, NROWS, D_MODEL, D_INNER);
}

// Round 3
// 1571.528 us; speedup vs baseline: 2.5447x; 1.6264x over previous
//
#include <hip/hip_runtime.h>
#include <math.h>

#define D_MODEL 1024
#define D_INNER 2048
#define D_STATE 16
#define DT_RANK 64
#define BATCH 4
#define SEQLEN 2048
#define NROWS (BATCH*SEQLEN)   // 8192
#define NCH   (BATCH*D_INNER)  // 8192 channels
#define NCHUNK 16
#define LCHUNK (SEQLEN/NCHUNK) // 128

typedef __attribute__((ext_vector_type(8))) short short8;
typedef __attribute__((ext_vector_type(4))) float f32x4;

__device__ __forceinline__ unsigned short bf16rn(float f) {
  unsigned int u = __float_as_uint(f);
  unsigned int r = (u + 0x7FFFu + ((u >> 16) & 1u)) >> 16;
  return (unsigned short)r;
}
__device__ __forceinline__ float bf16tof(unsigned short h) {
  return __uint_as_float(((unsigned int)h) << 16);
}

// ---------------------------------------------------------------------------
// Split-bf16 MFMA GEMM:  C[M,N] = A[M,K] * W[N,K]^T  (both K-contiguous).
// acc += hi*hi + hi*lo + lo*hi (3 MFMA) => ~fp32 accuracy at MFMA rate/3.
// 128x128 tile, BK=32, 4 waves (2x2), 16x16x32 bf16, 4x4 frags/wave.
// EPI: 0 = plain store (ldc=N); 1 = split x|z at D_INNER (ldc=D_INNER)
// ---------------------------------------------------------------------------
template<int EPI>
__global__ __launch_bounds__(256) void gemm_mfma(
    const float* __restrict__ A, const float* __restrict__ W,
    float* __restrict__ C0, float* __restrict__ C1,
    int M, int N, int K)
{
  __shared__ __align__(16) unsigned short As_hi[4][128][8];
  __shared__ __align__(16) unsigned short As_lo[4][128][8];
  __shared__ __align__(16) unsigned short Ws_hi[4][128][8];
  __shared__ __align__(16) unsigned short Ws_lo[4][128][8];

  const int tid = threadIdx.x;
  const int lane = tid & 63, wid = tid >> 6;
  const int wy = wid >> 1, wx = wid & 1;
  const int lr = lane & 15, lk = lane >> 4;
  const int row0 = blockIdx.y * 128, col0 = blockIdx.x * 128;

  const int qr = tid >> 3;
  const int qc = tid & 7;
  const float* Ag = A + (size_t)(row0 + qr) * K + qc * 4;
  const float* Wg = W + (size_t)(col0 + qr) * K + qc * 4;

  f32x4 acc[4][4];
#pragma unroll
  for (int i = 0; i < 4; i++)
#pragma unroll
    for (int j = 0; j < 4; j++) acc[i][j] = (f32x4){0.f, 0.f, 0.f, 0.f};

  float4 ar[4], wr_[4];

#define LOADT(K0)                                                     \
  {                                                                   \
    _Pragma("unroll")                                                 \
    for (int i = 0; i < 4; i++) {                                     \
      ar[i]  = *(const float4*)(Ag + (size_t)(32 * i) * K + (K0));    \
      wr_[i] = *(const float4*)(Wg + (size_t)(32 * i) * K + (K0));    \
    }                                                                 \
  }

  LOADT(0);
  const int KT = K >> 5;
  const int kb = qc >> 1, off = (qc & 1) * 4;

  for (int kt = 0; kt < KT; kt++) {
#pragma unroll
    for (int i = 0; i < 4; i++) {
      const int row = qr + 32 * i;
      {
        float4 v = ar[i];
        unsigned short h0 = bf16rn(v.x), h1 = bf16rn(v.y), h2 = bf16rn(v.z), h3 = bf16rn(v.w);
        unsigned short l0 = bf16rn(v.x - bf16tof(h0)), l1 = bf16rn(v.y - bf16tof(h1));
        unsigned short l2 = bf16rn(v.z - bf16tof(h2)), l3 = bf16rn(v.w - bf16tof(h3));
        *(uint2*)&As_hi[kb][row][off] = make_uint2(h0 | ((unsigned)h1 << 16), h2 | ((unsigned)h3 << 16));
        *(uint2*)&As_lo[kb][row][off] = make_uint2(l0 | ((unsigned)l1 << 16), l2 | ((unsigned)l3 << 16));
      }
      {
        float4 v = wr_[i];
        unsigned short h0 = bf16rn(v.x), h1 = bf16rn(v.y), h2 = bf16rn(v.z), h3 = bf16rn(v.w);
        unsigned short l0 = bf16rn(v.x - bf16tof(h0)), l1 = bf16rn(v.y - bf16tof(h1));
        unsigned short l2 = bf16rn(v.z - bf16tof(h2)), l3 = bf16rn(v.w - bf16tof(h3));
        *(uint2*)&Ws_hi[kb][row][off] = make_uint2(h0 | ((unsigned)h1 << 16), h2 | ((unsigned)h3 << 16));
        *(uint2*)&Ws_lo[kb][row][off] = make_uint2(l0 | ((unsigned)l1 << 16), l2 | ((unsigned)l3 << 16));
      }
    }
    if (kt + 1 < KT) LOADT((kt + 1) << 5);
    __syncthreads();

    short8 ah[4], al[4];
#pragma unroll
    for (int mi = 0; mi < 4; mi++) {
      ah[mi] = *(const short8*)&As_hi[lk][wy * 64 + mi * 16 + lr][0];
      al[mi] = *(const short8*)&As_lo[lk][wy * 64 + mi * 16 + lr][0];
    }
#pragma unroll
    for (int ni = 0; ni < 4; ni++) {
      const short8 bh = *(const short8*)&Ws_hi[lk][wx * 64 + ni * 16 + lr][0];
      const short8 bl = *(const short8*)&Ws_lo[lk][wx * 64 + ni * 16 + lr][0];
#pragma unroll
      for (int mi = 0; mi < 4; mi++) {
        acc[mi][ni] = __builtin_amdgcn_mfma_f32_16x16x32_bf16(ah[mi], bh, acc[mi][ni], 0, 0, 0);
        acc[mi][ni] = __builtin_amdgcn_mfma_f32_16x16x32_bf16(ah[mi], bl, acc[mi][ni], 0, 0, 0);
        acc[mi][ni] = __builtin_amdgcn_mfma_f32_16x16x32_bf16(al[mi], bh, acc[mi][ni], 0, 0, 0);
      }
    }
    __syncthreads();
  }
#undef LOADT

#pragma unroll
  for (int mi = 0; mi < 4; mi++)
#pragma unroll
    for (int ni = 0; ni < 4; ni++)
#pragma unroll
      for (int j = 0; j < 4; j++) {
        const int row = row0 + wy * 64 + mi * 16 + lk * 4 + j;
        const int col = col0 + wx * 64 + ni * 16 + lr;
        const float v = acc[mi][ni][j];
        if (EPI == 0) {
          C0[(size_t)row * N + col] = v;
        } else {
          if (col < D_INNER) C0[(size_t)row * D_INNER + col] = v;
          else               C1[(size_t)row * D_INNER + col - D_INNER] = v;
        }
      }
}

// ---------------------------------------------------------------------------
// fp32 VALU GEMM (small x_proj / dt_proj matmuls)
// EPI: 0 plain, 2 softplus(acc+bias)
// ---------------------------------------------------------------------------
template<int TM, int TN, int BK, int EPI>
__global__ __launch_bounds__(256) void gemm_bt(
    const float* __restrict__ A, const float* __restrict__ W,
    float* C0, const float* __restrict__ bias,
    int M, int N, int K, int lda)
{
  constexpr int BM = 16 * TM, BN = 16 * TN;
  __shared__ float As[BK][BM + 4];
  __shared__ float Ws[BK][BN + 4];

  const int tid = threadIdx.x;
  const int tx = tid & 15, ty = tid >> 4;
  const int row0 = blockIdx.y * BM, col0 = blockIdx.x * BN;

  float acc[TM][TN];
#pragma unroll
  for (int i = 0; i < TM; i++)
#pragma unroll
    for (int j = 0; j < TN; j++) acc[i][j] = 0.f;

  for (int k0 = 0; k0 < K; k0 += BK) {
    for (int i = tid; i < BM * BK; i += 256) {
      int m = i / BK, kk = i % BK;
      As[kk][m] = A[(size_t)(row0 + m) * lda + k0 + kk];
    }
    for (int i = tid; i < BN * BK; i += 256) {
      int nn = i / BK, kk = i % BK;
      Ws[kk][nn] = W[(size_t)(col0 + nn) * K + k0 + kk];
    }
    __syncthreads();
#pragma unroll
    for (int kk = 0; kk < BK; kk++) {
      float a[TM], bb[TN];
#pragma unroll
      for (int i = 0; i < TM; i++) a[i] = As[kk][ty * TM + i];
#pragma unroll
      for (int j = 0; j < TN; j++) bb[j] = Ws[kk][tx * TN + j];
#pragma unroll
      for (int i = 0; i < TM; i++)
#pragma unroll
        for (int j = 0; j < TN; j++)
          acc[i][j] = fmaf(a[i], bb[j], acc[i][j]);
    }
    __syncthreads();
  }

#pragma unroll
  for (int i = 0; i < TM; i++) {
    const int row = row0 + ty * TM + i;
#pragma unroll
    for (int j = 0; j < TN; j++) {
      const int col = col0 + tx * TN + j;
      float v = acc[i][j];
      if (EPI == 0) {
        C0[(size_t)row * N + col] = v;
      } else {
        float t = v + bias[col];
        float sp = (t > 20.f) ? t : log1pf(expf(t));
        C0[(size_t)row * N + col] = sp;
      }
    }
  }
}

// ---------------------------------------------------------------------------
// Causal depthwise conv1d (K=4) + bias + SiLU.  (B,L,D) d-contig.
// ---------------------------------------------------------------------------
__global__ __launch_bounds__(256) void conv_silu(
    const float* __restrict__ x, const float* __restrict__ w,
    const float* __restrict__ b, float* __restrict__ xs)
{
  const int idx = blockIdx.x * 256 + threadIdx.x;
  const int d = idx & (D_INNER - 1);
  const int bl = idx / D_INNER;
  const int l = bl & (SEQLEN - 1);
  float acc = b[d];
#pragma unroll
  for (int k = 0; k < 4; k++) {
    int ls = l + k - 3;
    if (ls >= 0) acc = fmaf(x[(size_t)(bl + k - 3) * D_INNER + d], w[d * 4 + k], acc);
  }
  xs[idx] = acc / (1.f + expf(-acc));
}

// ---------------------------------------------------------------------------
// Chunked selective scan, 3 passes.
// Group mapping (pass1/pass3): n = gid&15 (state), g = gid>>4,
//   ch = g & (NCH-1)  (d-major: 4 groups/wave = 4 consecutive d),
//   chunk = g >> 13.
// ---------------------------------------------------------------------------
__global__ __launch_bounds__(256) void scan_pass1(
    const float* __restrict__ dtb, const float* __restrict__ xs,
    const float* __restrict__ xdbl, const float* __restrict__ A_log,
    float* __restrict__ Pb, float* __restrict__ Sb)
{
  const int gid = blockIdx.x * 256 + threadIdx.x;
  const int n = gid & 15;
  const int g = gid >> 4;
  const int ch = g & (NCH - 1);
  const int chunk = g >> 13;
  const int d = ch & (D_INNER - 1);
  const int b = ch >> 11;

  const float Aval = -expf(A_log[d * D_STATE + n]);
  float P = 1.f, S = 0.f;
  const int l0 = chunk * LCHUNK;
#pragma unroll 4
  for (int l = l0; l < l0 + LCHUNK; l++) {
    const int rowi = b * SEQLEN + l;
    const size_t ix = (size_t)rowi * D_INNER + d;
    const float dtv = dtb[ix];
    const float xv  = xs[ix];
    const float Bv  = xdbl[(size_t)rowi * 96 + 64 + n];
    const float a = expf(dtv * Aval);
    P *= a;
    S = fmaf(S, a, dtv * xv * Bv);
  }
  Pb[(size_t)g * 16 + n] = P;
  Sb[(size_t)g * 16 + n] = S;
}

// Per (ch,n): exclusive scan over the 16 chunk transitions.
// Rewrites Sb to hold each chunk's INCOMING state.
__global__ __launch_bounds__(256) void scan_pass2(
    const float* __restrict__ Pb, float* __restrict__ Sb)
{
  const int gid = blockIdx.x * 256 + threadIdx.x;   // = ch*16 + n
  float I = 0.f;
#pragma unroll
  for (int c = 0; c < NCHUNK; c++) {
    const size_t idx = (size_t)gid + (size_t)c * NCH * 16;
    const float P = Pb[idx];
    const float S = Sb[idx];
    Sb[idx] = I;
    I = fmaf(I, P, S);
  }
}

__global__ __launch_bounds__(256) void scan_pass3(
    const float* dtb, const float* __restrict__ xs,
    const float* __restrict__ z, const float* __restrict__ xdbl,
    const float* __restrict__ A_log, const float* __restrict__ Dp,
    const float* __restrict__ Sb, float* y)
{
  const int gid = blockIdx.x * 256 + threadIdx.x;
  const int n = gid & 15;
  const int g = gid >> 4;
  const int ch = g & (NCH - 1);
  const int chunk = g >> 13;
  const int d = ch & (D_INNER - 1);
  const int b = ch >> 11;

  const float Aval = -expf(A_log[d * D_STATE + n]);
  const float Dval = Dp[d];
  float state = Sb[(size_t)g * 16 + n];
  const int l0 = chunk * LCHUNK;

#pragma unroll 2
  for (int l = l0; l < l0 + LCHUNK; l++) {
    const int rowi = b * SEQLEN + l;
    const size_t ix = (size_t)rowi * D_INNER + d;
    const float dtv = dtb[ix];
    const float xv  = xs[ix];
    const float zv  = z[ix];
    const float Bv  = xdbl[(size_t)rowi * 96 + 64 + n];
    const float Cv  = xdbl[(size_t)rowi * 96 + 80 + n];

    const float a = expf(dtv * Aval);
    state = fmaf(state, a, dtv * xv * Bv);

    float p = state * Cv;
    p += __shfl_xor(p, 8, 16);
    p += __shfl_xor(p, 4, 16);
    p += __shfl_xor(p, 2, 16);
    p += __shfl_xor(p, 1, 16);

    if (n == 0) {
      float yv = fmaf(xv, Dval, p);
      float gg = zv / (1.f + expf(-zv));
      y[ix] = yv * gg;
    }
  }
}

// ---------------------------------------------------------------------------
extern "C" void kernel_launch(void* const* d_in, const int* in_sizes, int n_in,
                              void* d_out, int out_size, void* d_ws, size_t ws_size,
                              hipStream_t stream)
{
  const float* hidden     = (const float*)d_in[0];
  const float* in_proj_w  = (const float*)d_in[1];
  const float* conv_w     = (const float*)d_in[2];
  const float* conv_b     = (const float*)d_in[3];
  const float* x_proj_w   = (const float*)d_in[4];
  const float* dt_proj_w  = (const float*)d_in[5];
  const float* dt_proj_b  = (const float*)d_in[6];
  const float* A_log      = (const float*)d_in[7];
  const float* Dparam     = (const float*)d_in[8];
  const float* out_proj_w = (const float*)d_in[9];
  float* out = (float*)d_out;

  const size_t NE = (size_t)NROWS * D_INNER;
  float* xbuf  = (float*)d_ws;            // x -> dt -> y (reused)
  float* zbuf  = xbuf + NE;
  float* xsbuf = zbuf + NE;
  float* xdbl  = xsbuf + NE;              // NROWS * 96
  float* Pb    = xdbl + (size_t)NROWS * 96;  // NCH*NCHUNK*16 = 2.1M floats
  float* Sb    = Pb + (size_t)NCH * NCHUNK * 16;

  // 1) in_proj (split-bf16 MFMA): -> x | z
  gemm_mfma<1><<<dim3((2 * D_INNER) / 128, NROWS / 128), 256, 0, stream>>>(
      hidden, in_proj_w, xbuf, zbuf, NROWS, 2 * D_INNER, D_MODEL);

  // 2) causal depthwise conv + SiLU
  conv_silu<<<(NROWS * D_INNER) / 256, 256, 0, stream>>>(xbuf, conv_w, conv_b, xsbuf);

  // 3) x_proj -> x_dbl
  gemm_bt<2, 6, 16, 0><<<dim3(1, NROWS / 32), 256, 0, stream>>>(
      xsbuf, x_proj_w, xdbl, nullptr, NROWS, 96, D_INNER, D_INNER);

  // 4) dt_proj + softplus -> dt (into xbuf)
  gemm_bt<8, 8, 16, 2><<<dim3(D_INNER / 128, NROWS / 128), 256, 0, stream>>>(
      xdbl, dt_proj_w, xbuf, dt_proj_b, NROWS, D_INNER, DT_RANK, 96);

  // 5) chunked selective scan (+ D-skip + z-gating); y overwrites dt in xbuf
  scan_pass1<<<(NCH * NCHUNK * 16) / 256, 256, 0, stream>>>(
      xbuf, xsbuf, xdbl, A_log, Pb, Sb);
  scan_pass2<<<(NCH * 16) / 256, 256, 0, stream>>>(Pb, Sb);
  scan_pass3<<<(NCH * NCHUNK * 16) / 256, 256, 0, stream>>>(
      xbuf, xsbuf, zbuf, xdbl, A_log, Dparam, Sb, xbuf);

  // 6) out_proj (split-bf16 MFMA) -> out
  gemm_mfma<0><<<dim3(D_MODEL / 128, NROWS / 128), 256, 0, stream>>>(
      xbuf, out_proj_w, out, nullptr, NROWS, D_MODEL, D_INNER);
}

// Round 5
// 1443.382 us; speedup vs baseline: 2.7706x; 1.0888x over previous
//
#include <hip/hip_runtime.h>
#include <math.h>

#define D_MODEL 1024
#define D_INNER 2048
#define D_STATE 16
#define DT_RANK 64
#define BATCH 4
#define SEQLEN 2048
#define NROWS (BATCH*SEQLEN)   // 8192
#define NCH   (BATCH*D_INNER)  // 8192 channels
#define NCHUNK 16
#define LCHUNK (SEQLEN/NCHUNK) // 128

typedef unsigned short u16;
typedef __attribute__((ext_vector_type(8))) short short8;
typedef __attribute__((ext_vector_type(4))) float f32x4;

__device__ __forceinline__ u16 bf16rn(float f) {
  unsigned int u = __float_as_uint(f);
  unsigned int r = (u + 0x7FFFu + ((u >> 16) & 1u)) >> 16;
  return (u16)r;
}
__device__ __forceinline__ float bf16tof(u16 h) {
  return __uint_as_float(((unsigned int)h) << 16);
}

// async global(16B/lane) -> LDS(wave-uniform base + lane*16)
__device__ __forceinline__ void gll16(const u16* g, u16* l) {
  __builtin_amdgcn_global_load_lds(
      (const __attribute__((address_space(1))) void*)g,
      (__attribute__((address_space(3))) void*)l, 16, 0, 0);
}

// ---------------------------------------------------------------------------
// split fp32 -> bf16 hi/lo planes (memory-bound, float4-wide)
// ---------------------------------------------------------------------------
__global__ __launch_bounds__(256) void split_planes(
    const float* __restrict__ in, u16* __restrict__ hi, u16* __restrict__ lo, int n4)
{
  const int i = blockIdx.x * 256 + threadIdx.x;
  if (i >= n4) return;
  const float4 v = ((const float4*)in)[i];
  const u16 h0 = bf16rn(v.x), h1 = bf16rn(v.y), h2 = bf16rn(v.z), h3 = bf16rn(v.w);
  const u16 l0 = bf16rn(v.x - bf16tof(h0)), l1 = bf16rn(v.y - bf16tof(h1));
  const u16 l2 = bf16rn(v.z - bf16tof(h2)), l3 = bf16rn(v.w - bf16tof(h3));
  ((ushort4*)hi)[i] = make_ushort4(h0, h1, h2, h3);
  ((ushort4*)lo)[i] = make_ushort4(l0, l1, l2, l3);
}

// ---------------------------------------------------------------------------
// Split-bf16 MFMA GEMM:  C[M,N] = A[M,K] * W[N,K]^T
// acc += hi*hi + hi*lo + lo*hi (3 MFMA) => ~fp32 accuracy.
// 128x128 tile, BK=32, 4 waves (2x2), 16x16x32 bf16, 4x4 frags/wave.
// CONVA=0: A from pre-split planes via global_load_lds (no conversion VALU)
// CONVA=1: A fp32 reg-staged + in-kernel split (for y which stays fp32)
// W always from pre-split planes via global_load_lds.
// EPI: 0 = plain store (ldc=N); 1 = x | silu(z) split at D_INNER (ldc=D_INNER)
// ---------------------------------------------------------------------------
template<int EPI, int CONVA>
__global__ __launch_bounds__(256) void gemm_mfma2(
    const float* __restrict__ Af,
    const u16* __restrict__ Ahi, const u16* __restrict__ Alo,
    const u16* __restrict__ Whi, const u16* __restrict__ Wlo,
    float* __restrict__ C0, float* __restrict__ C1,
    int M, int N, int K)
{
  __shared__ __align__(16) u16 As_hi[4][128][8];
  __shared__ __align__(16) u16 As_lo[4][128][8];
  __shared__ __align__(16) u16 Ws_hi[4][128][8];
  __shared__ __align__(16) u16 Ws_lo[4][128][8];

  const int tid = threadIdx.x;
  const int lane = tid & 63, wid = tid >> 6;
  const int wy = wid >> 1, wx = wid & 1;
  const int lr = lane & 15, lk = lane >> 4;
  const int row0 = blockIdx.y * 128, col0 = blockIdx.x * 128;

  // gll slot mapping: slot = kb*128 + row, two rounds of 256 slots
  const int s0 = wid * 64 + lane;
  const int rA0 = s0 & 127, kA0 = s0 >> 7;
  const int s1 = s0 + 256;
  const int rA1 = s1 & 127, kA1 = s1 >> 7;
  u16* ldsW_hi0 = &Ws_hi[0][0][0] + (size_t)(wid * 64) * 8;
  u16* ldsW_hi1 = &Ws_hi[0][0][0] + (size_t)(wid * 64 + 256) * 8;
  u16* ldsW_lo0 = &Ws_lo[0][0][0] + (size_t)(wid * 64) * 8;
  u16* ldsW_lo1 = &Ws_lo[0][0][0] + (size_t)(wid * 64 + 256) * 8;
  u16* ldsA_hi0 = &As_hi[0][0][0] + (size_t)(wid * 64) * 8;
  u16* ldsA_hi1 = &As_hi[0][0][0] + (size_t)(wid * 64 + 256) * 8;
  u16* ldsA_lo0 = &As_lo[0][0][0] + (size_t)(wid * 64) * 8;
  u16* ldsA_lo1 = &As_lo[0][0][0] + (size_t)(wid * 64 + 256) * 8;

  // fp32-A staging mapping (CONVA=1)
  const int qr = tid >> 3, qc = tid & 7;
  const int kb = qc >> 1, off = (qc & 1) * 4;
  const float* Ag = Af ? (Af + (size_t)(row0 + qr) * K + qc * 4) : nullptr;

  f32x4 acc[4][4];
#pragma unroll
  for (int i = 0; i < 4; i++)
#pragma unroll
    for (int j = 0; j < 4; j++) acc[i][j] = (f32x4){0.f, 0.f, 0.f, 0.f};

  float4 ar[4];
#define LOADT(K0)                                                   \
  {                                                                 \
    _Pragma("unroll")                                               \
    for (int i = 0; i < 4; i++)                                     \
      ar[i] = *(const float4*)(Ag + (size_t)(32 * i) * K + (K0));   \
  }

  if constexpr (CONVA) LOADT(0);

  const int KT = K >> 5;
  for (int kt = 0; kt < KT; kt++) {
    const int k0 = kt << 5;

    // W staging: async planes -> LDS (issue first, flies under A staging)
    gll16(Whi + (size_t)(col0 + rA0) * K + k0 + kA0 * 8, ldsW_hi0);
    gll16(Whi + (size_t)(col0 + rA1) * K + k0 + kA1 * 8, ldsW_hi1);
    gll16(Wlo + (size_t)(col0 + rA0) * K + k0 + kA0 * 8, ldsW_lo0);
    gll16(Wlo + (size_t)(col0 + rA1) * K + k0 + kA1 * 8, ldsW_lo1);

    if constexpr (CONVA) {
      // convert reg-staged fp32 A -> hi/lo LDS
#pragma unroll
      for (int i = 0; i < 4; i++) {
        const int row = qr + 32 * i;
        const float4 v = ar[i];
        const u16 h0 = bf16rn(v.x), h1 = bf16rn(v.y), h2 = bf16rn(v.z), h3 = bf16rn(v.w);
        const u16 l0 = bf16rn(v.x - bf16tof(h0)), l1 = bf16rn(v.y - bf16tof(h1));
        const u16 l2 = bf16rn(v.z - bf16tof(h2)), l3 = bf16rn(v.w - bf16tof(h3));
        *(uint2*)&As_hi[kb][row][off] = make_uint2(h0 | ((unsigned)h1 << 16), h2 | ((unsigned)h3 << 16));
        *(uint2*)&As_lo[kb][row][off] = make_uint2(l0 | ((unsigned)l1 << 16), l2 | ((unsigned)l3 << 16));
      }
      if (kt + 1 < KT) LOADT(k0 + 32);
    } else {
      gll16(Ahi + (size_t)(row0 + rA0) * K + k0 + kA0 * 8, ldsA_hi0);
      gll16(Ahi + (size_t)(row0 + rA1) * K + k0 + kA1 * 8, ldsA_hi1);
      gll16(Alo + (size_t)(row0 + rA0) * K + k0 + kA0 * 8, ldsA_lo0);
      gll16(Alo + (size_t)(row0 + rA1) * K + k0 + kA1 * 8, ldsA_lo1);
    }
    __syncthreads();

    short8 ah[4], al[4];
#pragma unroll
    for (int mi = 0; mi < 4; mi++) {
      ah[mi] = *(const short8*)&As_hi[lk][wy * 64 + mi * 16 + lr][0];
      al[mi] = *(const short8*)&As_lo[lk][wy * 64 + mi * 16 + lr][0];
    }
#pragma unroll
    for (int ni = 0; ni < 4; ni++) {
      const short8 bh = *(const short8*)&Ws_hi[lk][wx * 64 + ni * 16 + lr][0];
      const short8 bl = *(const short8*)&Ws_lo[lk][wx * 64 + ni * 16 + lr][0];
#pragma unroll
      for (int mi = 0; mi < 4; mi++) {
        acc[mi][ni] = __builtin_amdgcn_mfma_f32_16x16x32_bf16(ah[mi], bh, acc[mi][ni], 0, 0, 0);
        acc[mi][ni] = __builtin_amdgcn_mfma_f32_16x16x32_bf16(ah[mi], bl, acc[mi][ni], 0, 0, 0);
        acc[mi][ni] = __builtin_amdgcn_mfma_f32_16x16x32_bf16(al[mi], bh, acc[mi][ni], 0, 0, 0);
      }
    }
    __syncthreads();
  }
#undef LOADT

#pragma unroll
  for (int mi = 0; mi < 4; mi++)
#pragma unroll
    for (int ni = 0; ni < 4; ni++)
#pragma unroll
      for (int j = 0; j < 4; j++) {
        const int row = row0 + wy * 64 + mi * 16 + lk * 4 + j;
        const int col = col0 + wx * 64 + ni * 16 + lr;
        const float v = acc[mi][ni][j];
        if (EPI == 0) {
          C0[(size_t)row * N + col] = v;
        } else {
          if (col < D_INNER) C0[(size_t)row * D_INNER + col] = v;
          else C1[(size_t)row * D_INNER + col - D_INNER] = v / (1.f + __expf(-v));
        }
      }
}

// ---------------------------------------------------------------------------
// fp32 VALU GEMM (small x_proj / dt_proj matmuls)
// EPI: 0 plain, 2 softplus(acc+bias)
// ---------------------------------------------------------------------------
template<int TM, int TN, int BK, int EPI>
__global__ __launch_bounds__(256) void gemm_bt(
    const float* __restrict__ A, const float* __restrict__ W,
    float* C0, const float* __restrict__ bias,
    int M, int N, int K, int lda)
{
  constexpr int BM = 16 * TM, BN = 16 * TN;
  __shared__ float As[BK][BM + 4];
  __shared__ float Ws[BK][BN + 4];

  const int tid = threadIdx.x;
  const int tx = tid & 15, ty = tid >> 4;
  const int row0 = blockIdx.y * BM, col0 = blockIdx.x * BN;

  float acc[TM][TN];
#pragma unroll
  for (int i = 0; i < TM; i++)
#pragma unroll
    for (int j = 0; j < TN; j++) acc[i][j] = 0.f;

  for (int k0 = 0; k0 < K; k0 += BK) {
    for (int i = tid; i < BM * BK; i += 256) {
      int m = i / BK, kk = i % BK;
      As[kk][m] = A[(size_t)(row0 + m) * lda + k0 + kk];
    }
    for (int i = tid; i < BN * BK; i += 256) {
      int nn = i / BK, kk = i % BK;
      Ws[kk][nn] = W[(size_t)(col0 + nn) * K + k0 + kk];
    }
    __syncthreads();
#pragma unroll
    for (int kk = 0; kk < BK; kk++) {
      float a[TM], bb[TN];
#pragma unroll
      for (int i = 0; i < TM; i++) a[i] = As[kk][ty * TM + i];
#pragma unroll
      for (int j = 0; j < TN; j++) bb[j] = Ws[kk][tx * TN + j];
#pragma unroll
      for (int i = 0; i < TM; i++)
#pragma unroll
        for (int j = 0; j < TN; j++)
          acc[i][j] = fmaf(a[i], bb[j], acc[i][j]);
    }
    __syncthreads();
  }

#pragma unroll
  for (int i = 0; i < TM; i++) {
    const int row = row0 + ty * TM + i;
#pragma unroll
    for (int j = 0; j < TN; j++) {
      const int col = col0 + tx * TN + j;
      float v = acc[i][j];
      if (EPI == 0) {
        C0[(size_t)row * N + col] = v;
      } else {
        float t = v + bias[col];
        float sp = (t > 20.f) ? t : log1pf(expf(t));
        C0[(size_t)row * N + col] = sp;
      }
    }
  }
}

// ---------------------------------------------------------------------------
// Causal depthwise conv1d (K=4) + bias + SiLU.  (B,L,D) d-contig.
// ---------------------------------------------------------------------------
__global__ __launch_bounds__(256) void conv_silu(
    const float* __restrict__ x, const float* __restrict__ w,
    const float* __restrict__ b, float* __restrict__ xs)
{
  const int idx = blockIdx.x * 256 + threadIdx.x;
  const int d = idx & (D_INNER - 1);
  const int bl = idx / D_INNER;
  const int l = bl & (SEQLEN - 1);
  float acc = b[d];
#pragma unroll
  for (int k = 0; k < 4; k++) {
    int ls = l + k - 3;
    if (ls >= 0) acc = fmaf(x[(size_t)(bl + k - 3) * D_INNER + d], w[d * 4 + k], acc);
  }
  xs[idx] = acc / (1.f + __expf(-acc));
}

// ---------------------------------------------------------------------------
// Chunked selective scan, 3 passes. zbuf holds silu(z) (precomputed).
// ---------------------------------------------------------------------------
__global__ __launch_bounds__(256) void scan_pass1(
    const float* __restrict__ dtb, const float* __restrict__ xs,
    const float* __restrict__ xdbl, const float* __restrict__ A_log,
    float* __restrict__ Pb, float* __restrict__ Sb)
{
  const int gid = blockIdx.x * 256 + threadIdx.x;
  const int n = gid & 15;
  const int g = gid >> 4;
  const int ch = g & (NCH - 1);
  const int chunk = g >> 13;
  const int d = ch & (D_INNER - 1);
  const int b = ch >> 11;

  const float Aval = -__expf(A_log[d * D_STATE + n]);
  float P = 1.f, S = 0.f;
  const int l0 = chunk * LCHUNK;
  const size_t base = (size_t)(b * SEQLEN + l0) * D_INNER + d;
  const float* pdt = dtb + base;
  const float* pxs = xs + base;
  const float* pB = xdbl + (size_t)(b * SEQLEN + l0) * 96 + 64 + n;

#pragma unroll 4
  for (int l = 0; l < LCHUNK; l++) {
    const float dtv = *pdt; pdt += D_INNER;
    const float xv = *pxs;  pxs += D_INNER;
    const float Bv = *pB;   pB += 96;
    const float a = __expf(dtv * Aval);
    P *= a;
    S = fmaf(S, a, dtv * xv * Bv);
  }
  Pb[(size_t)g * 16 + n] = P;
  Sb[(size_t)g * 16 + n] = S;
}

// Per (ch,n): exclusive scan over chunk transitions -> incoming states.
__global__ __launch_bounds__(256) void scan_pass2(
    const float* __restrict__ Pb, float* __restrict__ Sb)
{
  const int gid = blockIdx.x * 256 + threadIdx.x;   // = ch*16 + n
  float I = 0.f;
#pragma unroll
  for (int c = 0; c < NCHUNK; c++) {
    const size_t idx = (size_t)gid + (size_t)c * NCH * 16;
    const float P = Pb[idx];
    const float S = Sb[idx];
    Sb[idx] = I;
    I = fmaf(I, P, S);
  }
}

__global__ __launch_bounds__(256) void scan_pass3(
    const float* dtb, const float* __restrict__ xs,
    const float* __restrict__ gz, const float* __restrict__ xdbl,
    const float* __restrict__ A_log, const float* __restrict__ Dp,
    const float* __restrict__ Sb, float* y)
{
  const int gid = blockIdx.x * 256 + threadIdx.x;
  const int n = gid & 15;
  const int g = gid >> 4;
  const int ch = g & (NCH - 1);
  const int chunk = g >> 13;
  const int d = ch & (D_INNER - 1);
  const int b = ch >> 11;

  const float Aval = -__expf(A_log[d * D_STATE + n]);
  const float Dval = Dp[d];
  float state = Sb[(size_t)g * 16 + n];
  const int l0 = chunk * LCHUNK;
  const size_t base = (size_t)(b * SEQLEN + l0) * D_INNER + d;
  const float* pdt = dtb + base;
  const float* pxs = xs + base;
  const float* pg = gz + base;
  const float* pB = xdbl + (size_t)(b * SEQLEN + l0) * 96 + 64 + n;
  float* py = y + base;

#pragma unroll 2
  for (int l = 0; l < LCHUNK; l++) {
    const float dtv = *pdt; pdt += D_INNER;
    const float xv = *pxs;  pxs += D_INNER;
    const float gv = *pg;   pg += D_INNER;
    const float Bv = pB[0];
    const float Cv = pB[16]; pB += 96;

    const float a = __expf(dtv * Aval);
    state = fmaf(state, a, dtv * xv * Bv);

    float p = state * Cv;
    p += __shfl_xor(p, 8, 16);
    p += __shfl_xor(p, 4, 16);
    p += __shfl_xor(p, 2, 16);
    p += __shfl_xor(p, 1, 16);

    if (n == 0) *py = fmaf(xv, Dval, p) * gv;
    py += D_INNER;
  }
}

// ---------------------------------------------------------------------------
// Workspace budget (must stay <= Round-3's proven 220.9 MB):
//   xbuf(67.1) zbuf(67.1) xsbuf(67.1) xdbl(3.1) Pb(8.4) Sb(8.4) = 220.9 MB
// Plane aliases (no extra memory):
//   hid/win planes (50.3 MB) live in xsbuf during steps 0-1 (xsbuf written
//   at step 2, planes dead by then).
//   wout planes (8.4 MB) live in zbuf, split AFTER pass3 (zbuf dead then).
// ---------------------------------------------------------------------------
extern "C" void kernel_launch(void* const* d_in, const int* in_sizes, int n_in,
                              void* d_out, int out_size, void* d_ws, size_t ws_size,
                              hipStream_t stream)
{
  const float* hidden     = (const float*)d_in[0];
  const float* in_proj_w  = (const float*)d_in[1];
  const float* conv_w     = (const float*)d_in[2];
  const float* conv_b     = (const float*)d_in[3];
  const float* x_proj_w   = (const float*)d_in[4];
  const float* dt_proj_w  = (const float*)d_in[5];
  const float* dt_proj_b  = (const float*)d_in[6];
  const float* A_log      = (const float*)d_in[7];
  const float* Dparam     = (const float*)d_in[8];
  const float* out_proj_w = (const float*)d_in[9];
  float* out = (float*)d_out;

  const size_t NE = (size_t)NROWS * D_INNER;      // 16.78M floats
  float* xbuf  = (float*)d_ws;                    // x -> dt -> y (reused)
  float* zbuf  = xbuf + NE;                       // silu(z); later wout planes
  float* xsbuf = zbuf + NE;                       // early: hid+win planes
  float* xdbl  = xsbuf + NE;                      // NROWS*96
  float* Pb    = xdbl + (size_t)NROWS * 96;
  float* Sb    = Pb + (size_t)NCH * NCHUNK * 16;

  // plane aliases
  u16* hidhi = (u16*)xsbuf;                            // 8.39M u16
  u16* hidlo = hidhi + (size_t)NROWS * D_MODEL;
  u16* winhi = hidlo + (size_t)NROWS * D_MODEL;        // 4.19M u16
  u16* winlo = winhi + (size_t)2 * D_INNER * D_MODEL;
  u16* wouthi = (u16*)zbuf;                            // 2.10M u16
  u16* woutlo = wouthi + (size_t)D_MODEL * D_INNER;

  // 0) pre-split fp32 -> bf16 hi/lo planes (hidden + in_proj_w)
  {
    int n4 = (NROWS * D_MODEL) / 4;
    split_planes<<<(n4 + 255) / 256, 256, 0, stream>>>(hidden, hidhi, hidlo, n4);
    n4 = (2 * D_INNER * D_MODEL) / 4;
    split_planes<<<(n4 + 255) / 256, 256, 0, stream>>>(in_proj_w, winhi, winlo, n4);
  }

  // 1) in_proj (plane-based MFMA): -> x | silu(z)
  gemm_mfma2<1, 0><<<dim3((2 * D_INNER) / 128, NROWS / 128), 256, 0, stream>>>(
      nullptr, hidhi, hidlo, winhi, winlo, xbuf, zbuf, NROWS, 2 * D_INNER, D_MODEL);

  // 2) causal depthwise conv + SiLU (overwrites the dead hid/win planes)
  conv_silu<<<(NROWS * D_INNER) / 256, 256, 0, stream>>>(xbuf, conv_w, conv_b, xsbuf);

  // 3) x_proj -> x_dbl
  gemm_bt<2, 6, 16, 0><<<dim3(1, NROWS / 32), 256, 0, stream>>>(
      xsbuf, x_proj_w, xdbl, nullptr, NROWS, 96, D_INNER, D_INNER);

  // 4) dt_proj + softplus -> dt (into xbuf)
  gemm_bt<8, 8, 16, 2><<<dim3(D_INNER / 128, NROWS / 128), 256, 0, stream>>>(
      xdbl, dt_proj_w, xbuf, dt_proj_b, NROWS, D_INNER, DT_RANK, 96);

  // 5) chunked selective scan; y overwrites dt in xbuf
  scan_pass1<<<(NCH * NCHUNK * 16) / 256, 256, 0, stream>>>(
      xbuf, xsbuf, xdbl, A_log, Pb, Sb);
  scan_pass2<<<(NCH * 16) / 256, 256, 0, stream>>>(Pb, Sb);
  scan_pass3<<<(NCH * NCHUNK * 16) / 256, 256, 0, stream>>>(
      xbuf, xsbuf, zbuf, xdbl, A_log, Dparam, Sb, xbuf);

  // 5.5) split out_proj_w planes into zbuf (dead after pass3)
  {
    const int n4 = (D_MODEL * D_INNER) / 4;
    split_planes<<<(n4 + 255) / 256, 256, 0, stream>>>(out_proj_w, wouthi, woutlo, n4);
  }

  // 6) out_proj (A fp32-convert, W planes) -> out
  gemm_mfma2<0, 1><<<dim3(D_MODEL / 128, NROWS / 128), 256, 0, stream>>>(
      xbuf, nullptr, nullptr, wouthi, woutlo, out, nullptr, NROWS, D_MODEL, D_INNER);
}

// Round 6
// 1161.613 us; speedup vs baseline: 3.4426x; 1.2426x over previous
//
#include <hip/hip_runtime.h>
#include <math.h>

#define D_MODEL 1024
#define D_INNER 2048
#define D_STATE 16
#define DT_RANK 64
#define BATCH 4
#define SEQLEN 2048
#define NROWS (BATCH*SEQLEN)   // 8192
#define NCH   (BATCH*D_INNER)  // 8192 channels
#define NCHUNK 32
#define LCHUNK (SEQLEN/NCHUNK) // 64

typedef unsigned short u16;
typedef __attribute__((ext_vector_type(8))) short short8;
typedef __attribute__((ext_vector_type(4))) float f32x4;

__device__ __forceinline__ u16 bf16rn(float f) {
  unsigned int u = __float_as_uint(f);
  unsigned int r = (u + 0x7FFFu + ((u >> 16) & 1u)) >> 16;
  return (u16)r;
}
__device__ __forceinline__ float bf16tof(u16 h) {
  return __uint_as_float(((unsigned int)h) << 16);
}

// async global(16B/lane) -> LDS(wave-uniform base + lane*16)
__device__ __forceinline__ void gll16(const u16* g, u16* l) {
  __builtin_amdgcn_global_load_lds(
      (const __attribute__((address_space(1))) void*)g,
      (__attribute__((address_space(3))) void*)l, 16, 0, 0);
}

// ---------------------------------------------------------------------------
// split fp32 -> bf16 hi/lo planes (memory-bound, float4-wide)
// ---------------------------------------------------------------------------
__global__ __launch_bounds__(256) void split_planes(
    const float* __restrict__ in, u16* __restrict__ hi, u16* __restrict__ lo, int n4)
{
  const int i = blockIdx.x * 256 + threadIdx.x;
  if (i >= n4) return;
  const float4 v = ((const float4*)in)[i];
  const u16 h0 = bf16rn(v.x), h1 = bf16rn(v.y), h2 = bf16rn(v.z), h3 = bf16rn(v.w);
  const u16 l0 = bf16rn(v.x - bf16tof(h0)), l1 = bf16rn(v.y - bf16tof(h1));
  const u16 l2 = bf16rn(v.z - bf16tof(h2)), l3 = bf16rn(v.w - bf16tof(h3));
  ((ushort4*)hi)[i] = make_ushort4(h0, h1, h2, h3);
  ((ushort4*)lo)[i] = make_ushort4(l0, l1, l2, l3);
}

// ---------------------------------------------------------------------------
// Split-bf16 MFMA GEMM:  C[M,N] = A[M,K] * W[N,K]^T   (unchanged from R5)
// ---------------------------------------------------------------------------
template<int EPI, int CONVA>
__global__ __launch_bounds__(256) void gemm_mfma2(
    const float* __restrict__ Af,
    const u16* __restrict__ Ahi, const u16* __restrict__ Alo,
    const u16* __restrict__ Whi, const u16* __restrict__ Wlo,
    float* __restrict__ C0, float* __restrict__ C1,
    int M, int N, int K)
{
  __shared__ __align__(16) u16 As_hi[4][128][8];
  __shared__ __align__(16) u16 As_lo[4][128][8];
  __shared__ __align__(16) u16 Ws_hi[4][128][8];
  __shared__ __align__(16) u16 Ws_lo[4][128][8];

  const int tid = threadIdx.x;
  const int lane = tid & 63, wid = tid >> 6;
  const int wy = wid >> 1, wx = wid & 1;
  const int lr = lane & 15, lk = lane >> 4;
  const int row0 = blockIdx.y * 128, col0 = blockIdx.x * 128;

  const int s0 = wid * 64 + lane;
  const int rA0 = s0 & 127, kA0 = s0 >> 7;
  const int s1 = s0 + 256;
  const int rA1 = s1 & 127, kA1 = s1 >> 7;
  u16* ldsW_hi0 = &Ws_hi[0][0][0] + (size_t)(wid * 64) * 8;
  u16* ldsW_hi1 = &Ws_hi[0][0][0] + (size_t)(wid * 64 + 256) * 8;
  u16* ldsW_lo0 = &Ws_lo[0][0][0] + (size_t)(wid * 64) * 8;
  u16* ldsW_lo1 = &Ws_lo[0][0][0] + (size_t)(wid * 64 + 256) * 8;
  u16* ldsA_hi0 = &As_hi[0][0][0] + (size_t)(wid * 64) * 8;
  u16* ldsA_hi1 = &As_hi[0][0][0] + (size_t)(wid * 64 + 256) * 8;
  u16* ldsA_lo0 = &As_lo[0][0][0] + (size_t)(wid * 64) * 8;
  u16* ldsA_lo1 = &As_lo[0][0][0] + (size_t)(wid * 64 + 256) * 8;

  const int qr = tid >> 3, qc = tid & 7;
  const int kb = qc >> 1, off = (qc & 1) * 4;
  const float* Ag = Af ? (Af + (size_t)(row0 + qr) * K + qc * 4) : nullptr;

  f32x4 acc[4][4];
#pragma unroll
  for (int i = 0; i < 4; i++)
#pragma unroll
    for (int j = 0; j < 4; j++) acc[i][j] = (f32x4){0.f, 0.f, 0.f, 0.f};

  float4 ar[4];
#define LOADT(K0)                                                   \
  {                                                                 \
    _Pragma("unroll")                                               \
    for (int i = 0; i < 4; i++)                                     \
      ar[i] = *(const float4*)(Ag + (size_t)(32 * i) * K + (K0));   \
  }

  if constexpr (CONVA) LOADT(0);

  const int KT = K >> 5;
  for (int kt = 0; kt < KT; kt++) {
    const int k0 = kt << 5;

    gll16(Whi + (size_t)(col0 + rA0) * K + k0 + kA0 * 8, ldsW_hi0);
    gll16(Whi + (size_t)(col0 + rA1) * K + k0 + kA1 * 8, ldsW_hi1);
    gll16(Wlo + (size_t)(col0 + rA0) * K + k0 + kA0 * 8, ldsW_lo0);
    gll16(Wlo + (size_t)(col0 + rA1) * K + k0 + kA1 * 8, ldsW_lo1);

    if constexpr (CONVA) {
#pragma unroll
      for (int i = 0; i < 4; i++) {
        const int row = qr + 32 * i;
        const float4 v = ar[i];
        const u16 h0 = bf16rn(v.x), h1 = bf16rn(v.y), h2 = bf16rn(v.z), h3 = bf16rn(v.w);
        const u16 l0 = bf16rn(v.x - bf16tof(h0)), l1 = bf16rn(v.y - bf16tof(h1));
        const u16 l2 = bf16rn(v.z - bf16tof(h2)), l3 = bf16rn(v.w - bf16tof(h3));
        *(uint2*)&As_hi[kb][row][off] = make_uint2(h0 | ((unsigned)h1 << 16), h2 | ((unsigned)h3 << 16));
        *(uint2*)&As_lo[kb][row][off] = make_uint2(l0 | ((unsigned)l1 << 16), l2 | ((unsigned)l3 << 16));
      }
      if (kt + 1 < KT) LOADT(k0 + 32);
    } else {
      gll16(Ahi + (size_t)(row0 + rA0) * K + k0 + kA0 * 8, ldsA_hi0);
      gll16(Ahi + (size_t)(row0 + rA1) * K + k0 + kA1 * 8, ldsA_hi1);
      gll16(Alo + (size_t)(row0 + rA0) * K + k0 + kA0 * 8, ldsA_lo0);
      gll16(Alo + (size_t)(row0 + rA1) * K + k0 + kA1 * 8, ldsA_lo1);
    }
    __syncthreads();

    short8 ah[4], al[4];
#pragma unroll
    for (int mi = 0; mi < 4; mi++) {
      ah[mi] = *(const short8*)&As_hi[lk][wy * 64 + mi * 16 + lr][0];
      al[mi] = *(const short8*)&As_lo[lk][wy * 64 + mi * 16 + lr][0];
    }
#pragma unroll
    for (int ni = 0; ni < 4; ni++) {
      const short8 bh = *(const short8*)&Ws_hi[lk][wx * 64 + ni * 16 + lr][0];
      const short8 bl = *(const short8*)&Ws_lo[lk][wx * 64 + ni * 16 + lr][0];
#pragma unroll
      for (int mi = 0; mi < 4; mi++) {
        acc[mi][ni] = __builtin_amdgcn_mfma_f32_16x16x32_bf16(ah[mi], bh, acc[mi][ni], 0, 0, 0);
        acc[mi][ni] = __builtin_amdgcn_mfma_f32_16x16x32_bf16(ah[mi], bl, acc[mi][ni], 0, 0, 0);
        acc[mi][ni] = __builtin_amdgcn_mfma_f32_16x16x32_bf16(al[mi], bh, acc[mi][ni], 0, 0, 0);
      }
    }
    __syncthreads();
  }
#undef LOADT

#pragma unroll
  for (int mi = 0; mi < 4; mi++)
#pragma unroll
    for (int ni = 0; ni < 4; ni++)
#pragma unroll
      for (int j = 0; j < 4; j++) {
        const int row = row0 + wy * 64 + mi * 16 + lk * 4 + j;
        const int col = col0 + wx * 64 + ni * 16 + lr;
        const float v = acc[mi][ni][j];
        if (EPI == 0) {
          C0[(size_t)row * N + col] = v;
        } else {
          if (col < D_INNER) C0[(size_t)row * D_INNER + col] = v;
          else C1[(size_t)row * D_INNER + col - D_INNER] = v / (1.f + __expf(-v));
        }
      }
}

// ---------------------------------------------------------------------------
// fp32 VALU GEMM (small x_proj / dt_proj matmuls)
// ---------------------------------------------------------------------------
template<int TM, int TN, int BK, int EPI>
__global__ __launch_bounds__(256) void gemm_bt(
    const float* __restrict__ A, const float* __restrict__ W,
    float* C0, const float* __restrict__ bias,
    int M, int N, int K, int lda)
{
  constexpr int BM = 16 * TM, BN = 16 * TN;
  __shared__ float As[BK][BM + 4];
  __shared__ float Ws[BK][BN + 4];

  const int tid = threadIdx.x;
  const int tx = tid & 15, ty = tid >> 4;
  const int row0 = blockIdx.y * BM, col0 = blockIdx.x * BN;

  float acc[TM][TN];
#pragma unroll
  for (int i = 0; i < TM; i++)
#pragma unroll
    for (int j = 0; j < TN; j++) acc[i][j] = 0.f;

  for (int k0 = 0; k0 < K; k0 += BK) {
    for (int i = tid; i < BM * BK; i += 256) {
      int m = i / BK, kk = i % BK;
      As[kk][m] = A[(size_t)(row0 + m) * lda + k0 + kk];
    }
    for (int i = tid; i < BN * BK; i += 256) {
      int nn = i / BK, kk = i % BK;
      Ws[kk][nn] = W[(size_t)(col0 + nn) * K + k0 + kk];
    }
    __syncthreads();
#pragma unroll
    for (int kk = 0; kk < BK; kk++) {
      float a[TM], bb[TN];
#pragma unroll
      for (int i = 0; i < TM; i++) a[i] = As[kk][ty * TM + i];
#pragma unroll
      for (int j = 0; j < TN; j++) bb[j] = Ws[kk][tx * TN + j];
#pragma unroll
      for (int i = 0; i < TM; i++)
#pragma unroll
        for (int j = 0; j < TN; j++)
          acc[i][j] = fmaf(a[i], bb[j], acc[i][j]);
    }
    __syncthreads();
  }

#pragma unroll
  for (int i = 0; i < TM; i++) {
    const int row = row0 + ty * TM + i;
#pragma unroll
    for (int j = 0; j < TN; j++) {
      const int col = col0 + tx * TN + j;
      float v = acc[i][j];
      if (EPI == 0) {
        C0[(size_t)row * N + col] = v;
      } else {
        float t = v + bias[col];
        float sp = (t > 20.f) ? t : log1pf(expf(t));
        C0[(size_t)row * N + col] = sp;
      }
    }
  }
}

// ---------------------------------------------------------------------------
// Causal depthwise conv1d (K=4) + bias + SiLU.  (B,L,D) d-contig.
// ---------------------------------------------------------------------------
__global__ __launch_bounds__(256) void conv_silu(
    const float* __restrict__ x, const float* __restrict__ w,
    const float* __restrict__ b, float* __restrict__ xs)
{
  const int idx = blockIdx.x * 256 + threadIdx.x;
  const int d = idx & (D_INNER - 1);
  const int bl = idx / D_INNER;
  const int l = bl & (SEQLEN - 1);
  float acc = b[d];
#pragma unroll
  for (int k = 0; k < 4; k++) {
    int ls = l + k - 3;
    if (ls >= 0) acc = fmaf(x[(size_t)(bl + k - 3) * D_INNER + d], w[d * 4 + k], acc);
  }
  xs[idx] = acc / (1.f + __expf(-acc));
}

// ---------------------------------------------------------------------------
// Chunked selective scan, lane-owns-channel: each lane holds all 16 states
// of one (b, d, chunk) in registers. No cross-lane ops. 64 consecutive d per
// wave => dt/xs/gz/y fully coalesced; B/C rows block-uniform (L1 broadcast).
// Mapping: gid = blk*256+tid; d = gid & 2047; rest = gid>>11 (block-uniform);
//          b = rest>>5 (NCHUNK=32), chunk = rest&31.
// ---------------------------------------------------------------------------
__global__ __launch_bounds__(256) void scan_pass1(
    const float* __restrict__ dtb, const float* __restrict__ xs,
    const float* __restrict__ xdbl, const float* __restrict__ A_log,
    float* __restrict__ Pb, float* __restrict__ Sb)
{
  const int gid = blockIdx.x * 256 + threadIdx.x;
  const int d = gid & (D_INNER - 1);
  const int rest = gid >> 11;
  const int b = rest >> 5;
  const int chunk = rest & (NCHUNK - 1);

  float Av[16];
#pragma unroll
  for (int i = 0; i < 4; i++) {
    const f32x4 a4 = *(const f32x4*)(A_log + d * D_STATE + i * 4);
#pragma unroll
    for (int j = 0; j < 4; j++) Av[i * 4 + j] = -__expf(a4[j]);
  }

  float P[16], S[16];
#pragma unroll
  for (int n = 0; n < 16; n++) { P[n] = 1.f; S[n] = 0.f; }

  const int l0 = chunk * LCHUNK;
  const size_t base = (size_t)(b * SEQLEN + l0) * D_INNER + d;
  const float* pdt = dtb + base;
  const float* pxs = xs + base;
  const float* pB = xdbl + (size_t)(b * SEQLEN + l0) * 96 + 64;

#pragma unroll 2
  for (int l = 0; l < LCHUNK; l++) {
    const float dtv = *pdt; pdt += D_INNER;
    const float xv  = *pxs; pxs += D_INNER;
    f32x4 B4[4];
#pragma unroll
    for (int i = 0; i < 4; i++) B4[i] = *(const f32x4*)(pB + 4 * i);
    pB += 96;
    const float u = dtv * xv;
#pragma unroll
    for (int n = 0; n < 16; n++) {
      const float a = __expf(dtv * Av[n]);
      P[n] *= a;
      S[n] = fmaf(S[n], a, u * B4[n >> 2][n & 3]);
    }
  }

  const size_t ob = ((size_t)chunk * NCH + (size_t)b * D_INNER + d) * 16;
#pragma unroll
  for (int i = 0; i < 4; i++) {
    *(f32x4*)(Pb + ob + 4 * i) = (f32x4){P[4*i], P[4*i+1], P[4*i+2], P[4*i+3]};
    *(f32x4*)(Sb + ob + 4 * i) = (f32x4){S[4*i], S[4*i+1], S[4*i+2], S[4*i+3]};
  }
}

// Per (ch,n): exclusive scan over chunk transitions -> incoming states.
__global__ __launch_bounds__(256) void scan_pass2(
    const float* __restrict__ Pb, float* __restrict__ Sb)
{
  const int gid = blockIdx.x * 256 + threadIdx.x;   // = ch*16 + n
  float I = 0.f;
#pragma unroll
  for (int c = 0; c < NCHUNK; c++) {
    const size_t idx = (size_t)gid + (size_t)c * NCH * 16;
    const float P = Pb[idx];
    const float S = Sb[idx];
    Sb[idx] = I;
    I = fmaf(I, P, S);
  }
}

__global__ __launch_bounds__(256) void scan_pass3(
    const float* dtb, const float* __restrict__ xs,
    const float* __restrict__ gz, const float* __restrict__ xdbl,
    const float* __restrict__ A_log, const float* __restrict__ Dp,
    const float* __restrict__ Sb, float* y)
{
  const int gid = blockIdx.x * 256 + threadIdx.x;
  const int d = gid & (D_INNER - 1);
  const int rest = gid >> 11;
  const int b = rest >> 5;
  const int chunk = rest & (NCHUNK - 1);

  float Av[16];
#pragma unroll
  for (int i = 0; i < 4; i++) {
    const f32x4 a4 = *(const f32x4*)(A_log + d * D_STATE + i * 4);
#pragma unroll
    for (int j = 0; j < 4; j++) Av[i * 4 + j] = -__expf(a4[j]);
  }
  const float Dval = Dp[d];

  float S[16];
  const size_t sb = ((size_t)chunk * NCH + (size_t)b * D_INNER + d) * 16;
#pragma unroll
  for (int i = 0; i < 4; i++) {
    const f32x4 s4 = *(const f32x4*)(Sb + sb + 4 * i);
#pragma unroll
    for (int j = 0; j < 4; j++) S[i * 4 + j] = s4[j];
  }

  const int l0 = chunk * LCHUNK;
  const size_t base = (size_t)(b * SEQLEN + l0) * D_INNER + d;
  const float* pdt = dtb + base;
  const float* pxs = xs + base;
  const float* pg  = gz + base;
  const float* pB  = xdbl + (size_t)(b * SEQLEN + l0) * 96 + 64;
  float* py = y + base;

#pragma unroll 2
  for (int l = 0; l < LCHUNK; l++) {
    const float dtv = *pdt; pdt += D_INNER;
    const float xv  = *pxs; pxs += D_INNER;
    const float gv  = *pg;  pg += D_INNER;
    f32x4 B4[4], C4[4];
#pragma unroll
    for (int i = 0; i < 4; i++) B4[i] = *(const f32x4*)(pB + 4 * i);
#pragma unroll
    for (int i = 0; i < 4; i++) C4[i] = *(const f32x4*)(pB + 16 + 4 * i);
    pB += 96;

    const float u = dtv * xv;
    float yv = xv * Dval;
#pragma unroll
    for (int n = 0; n < 16; n++) {
      const float a = __expf(dtv * Av[n]);
      S[n] = fmaf(S[n], a, u * B4[n >> 2][n & 3]);
      yv = fmaf(S[n], C4[n >> 2][n & 3], yv);
    }
    *py = yv * gv;
    py += D_INNER;
  }
}

// ---------------------------------------------------------------------------
// Workspace: xbuf(67.1) zbuf(67.1) xsbuf(67.1) xdbl(3.1) = 204.4 MB (proven).
// Pb/Sb (16.8 MB each) alias d_out (33.5 MB): dead before out_proj fully
// overwrites d_out. Plane aliases as in R5.
// ---------------------------------------------------------------------------
extern "C" void kernel_launch(void* const* d_in, const int* in_sizes, int n_in,
                              void* d_out, int out_size, void* d_ws, size_t ws_size,
                              hipStream_t stream)
{
  const float* hidden     = (const float*)d_in[0];
  const float* in_proj_w  = (const float*)d_in[1];
  const float* conv_w     = (const float*)d_in[2];
  const float* conv_b     = (const float*)d_in[3];
  const float* x_proj_w   = (const float*)d_in[4];
  const float* dt_proj_w  = (const float*)d_in[5];
  const float* dt_proj_b  = (const float*)d_in[6];
  const float* A_log      = (const float*)d_in[7];
  const float* Dparam     = (const float*)d_in[8];
  const float* out_proj_w = (const float*)d_in[9];
  float* out = (float*)d_out;

  const size_t NE = (size_t)NROWS * D_INNER;      // 16.78M floats
  float* xbuf  = (float*)d_ws;                    // x -> dt -> y (reused)
  float* zbuf  = xbuf + NE;                       // silu(z); later wout planes
  float* xsbuf = zbuf + NE;                       // early: hid+win planes
  float* xdbl  = xsbuf + NE;                      // NROWS*96

  // Pb/Sb live in d_out (exactly 2 * NCH*NCHUNK*16 = 8.39M floats = out_size)
  float* Pb = out;
  float* Sb = out + (size_t)NCH * NCHUNK * 16;

  // plane aliases
  u16* hidhi = (u16*)xsbuf;
  u16* hidlo = hidhi + (size_t)NROWS * D_MODEL;
  u16* winhi = hidlo + (size_t)NROWS * D_MODEL;
  u16* winlo = winhi + (size_t)2 * D_INNER * D_MODEL;
  u16* wouthi = (u16*)zbuf;
  u16* woutlo = wouthi + (size_t)D_MODEL * D_INNER;

  // 0) pre-split fp32 -> bf16 hi/lo planes (hidden + in_proj_w)
  {
    int n4 = (NROWS * D_MODEL) / 4;
    split_planes<<<(n4 + 255) / 256, 256, 0, stream>>>(hidden, hidhi, hidlo, n4);
    n4 = (2 * D_INNER * D_MODEL) / 4;
    split_planes<<<(n4 + 255) / 256, 256, 0, stream>>>(in_proj_w, winhi, winlo, n4);
  }

  // 1) in_proj (plane-based MFMA): -> x | silu(z)
  gemm_mfma2<1, 0><<<dim3((2 * D_INNER) / 128, NROWS / 128), 256, 0, stream>>>(
      nullptr, hidhi, hidlo, winhi, winlo, xbuf, zbuf, NROWS, 2 * D_INNER, D_MODEL);

  // 2) causal depthwise conv + SiLU (overwrites the dead hid/win planes)
  conv_silu<<<(NROWS * D_INNER) / 256, 256, 0, stream>>>(xbuf, conv_w, conv_b, xsbuf);

  // 3) x_proj -> x_dbl
  gemm_bt<2, 6, 16, 0><<<dim3(1, NROWS / 32), 256, 0, stream>>>(
      xsbuf, x_proj_w, xdbl, nullptr, NROWS, 96, D_INNER, D_INNER);

  // 4) dt_proj + softplus -> dt (into xbuf)
  gemm_bt<8, 8, 16, 2><<<dim3(D_INNER / 128, NROWS / 128), 256, 0, stream>>>(
      xdbl, dt_proj_w, xbuf, dt_proj_b, NROWS, D_INNER, DT_RANK, 96);

  // 5) chunked selective scan (lane-owns-channel); y overwrites dt in xbuf
  scan_pass1<<<(NCH * NCHUNK) / 256, 256, 0, stream>>>(
      xbuf, xsbuf, xdbl, A_log, Pb, Sb);
  scan_pass2<<<(NCH * 16) / 256, 256, 0, stream>>>(Pb, Sb);
  scan_pass3<<<(NCH * NCHUNK) / 256, 256, 0, stream>>>(
      xbuf, xsbuf, zbuf, xdbl, A_log, Dparam, Sb, xbuf);

  // 5.5) split out_proj_w planes into zbuf (dead after pass3)
  {
    const int n4 = (D_MODEL * D_INNER) / 4;
    split_planes<<<(n4 + 255) / 256, 256, 0, stream>>>(out_proj_w, wouthi, woutlo, n4);
  }

  // 6) out_proj (A fp32-convert, W planes) -> out  (overwrites Pb/Sb)
  gemm_mfma2<0, 1><<<dim3(D_MODEL / 128, NROWS / 128), 256, 0, stream>>>(
      xbuf, nullptr, nullptr, wouthi, woutlo, out, nullptr, NROWS, D_MODEL, D_INNER);
}

// Round 7
// 826.682 us; speedup vs baseline: 4.8374x; 1.4052x over previous
//
#include <hip/hip_runtime.h>
#include <math.h>

#define D_MODEL 1024
#define D_INNER 2048
#define D_STATE 16
#define DT_RANK 64
#define BATCH 4
#define SEQLEN 2048
#define NROWS (BATCH*SEQLEN)   // 8192
#define NCH   (BATCH*D_INNER)  // 8192 channels
#define NCHUNK 32
#define LCHUNK (SEQLEN/NCHUNK) // 64
#define XP_N 96                // x_proj output cols
#define XP_KS 16               // x_proj K-split slices

typedef unsigned short u16;
typedef __attribute__((ext_vector_type(8))) short short8;
typedef __attribute__((ext_vector_type(4))) float f32x4;

__device__ __forceinline__ u16 bf16rn(float f) {
  unsigned int u = __float_as_uint(f);
  unsigned int r = (u + 0x7FFFu + ((u >> 16) & 1u)) >> 16;
  return (u16)r;
}
__device__ __forceinline__ float bf16tof(u16 h) {
  return __uint_as_float(((unsigned int)h) << 16);
}

// async global(16B/lane) -> LDS(wave-uniform base + lane*16)
__device__ __forceinline__ void gll16(const u16* g, u16* l) {
  __builtin_amdgcn_global_load_lds(
      (const __attribute__((address_space(1))) void*)g,
      (__attribute__((address_space(3))) void*)l, 16, 0, 0);
}

// ---------------------------------------------------------------------------
// split fp32 -> bf16 hi/lo planes (memory-bound, float4-wide)
// ---------------------------------------------------------------------------
__global__ __launch_bounds__(256) void split_planes(
    const float* __restrict__ in, u16* __restrict__ hi, u16* __restrict__ lo, int n4)
{
  const int i = blockIdx.x * 256 + threadIdx.x;
  if (i >= n4) return;
  const float4 v = ((const float4*)in)[i];
  const u16 h0 = bf16rn(v.x), h1 = bf16rn(v.y), h2 = bf16rn(v.z), h3 = bf16rn(v.w);
  const u16 l0 = bf16rn(v.x - bf16tof(h0)), l1 = bf16rn(v.y - bf16tof(h1));
  const u16 l2 = bf16rn(v.z - bf16tof(h2)), l3 = bf16rn(v.w - bf16tof(h3));
  ((ushort4*)hi)[i] = make_ushort4(h0, h1, h2, h3);
  ((ushort4*)lo)[i] = make_ushort4(l0, l1, l2, l3);
}

// ---------------------------------------------------------------------------
// Split-bf16 MFMA GEMM:  C[M,N] = A[M,K] * W[N,K]^T
// acc += hi*hi + hi*lo + lo*hi (3 MFMA) => ~fp32 accuracy.
// 128x128 tile, BK=32, 4 waves (2x2), 16x16x32 bf16, 4x4 frags/wave.
// CONVA=0: A from pre-split planes via global_load_lds (lda = plane row len)
// CONVA=1: A fp32 reg-staged + in-kernel split (lda = fp32 row len)
// W always from pre-split planes (row len = K).
// Split-K: blockIdx.z = ks, slice len = K/KS.
// EPI: 0 plain store (ldc=N)
//      1 x | silu(z) split at D_INNER (ldc=D_INNER)
//      2 softplus(acc + bias[col]) (ldc=N)
//      3 K-split partial: C0[(ks*M + row)*XP_N + col], col<XP_N only
// ---------------------------------------------------------------------------
template<int EPI, int CONVA>
__global__ __launch_bounds__(256) void gemm_mfma2(
    const float* __restrict__ Af,
    const u16* __restrict__ Ahi, const u16* __restrict__ Alo,
    const u16* __restrict__ Whi, const u16* __restrict__ Wlo,
    float* __restrict__ C0, float* __restrict__ C1,
    const float* __restrict__ bias,
    int M, int N, int K, int lda, int KS)
{
  __shared__ __align__(16) u16 As_hi[4][128][8];
  __shared__ __align__(16) u16 As_lo[4][128][8];
  __shared__ __align__(16) u16 Ws_hi[4][128][8];
  __shared__ __align__(16) u16 Ws_lo[4][128][8];

  const int tid = threadIdx.x;
  const int lane = tid & 63, wid = tid >> 6;
  const int wy = wid >> 1, wx = wid & 1;
  const int lr = lane & 15, lk = lane >> 4;
  const int row0 = blockIdx.y * 128, col0 = blockIdx.x * 128;
  const int ks = blockIdx.z;
  const int klen = K / KS, kbeg = ks * klen;
  const int KT = klen >> 5;

  const int s0 = wid * 64 + lane;
  const int rA0 = s0 & 127, kA0 = s0 >> 7;
  const int s1 = s0 + 256;
  const int rA1 = s1 & 127, kA1 = s1 >> 7;
  u16* ldsW_hi0 = &Ws_hi[0][0][0] + (size_t)(wid * 64) * 8;
  u16* ldsW_hi1 = &Ws_hi[0][0][0] + (size_t)(wid * 64 + 256) * 8;
  u16* ldsW_lo0 = &Ws_lo[0][0][0] + (size_t)(wid * 64) * 8;
  u16* ldsW_lo1 = &Ws_lo[0][0][0] + (size_t)(wid * 64 + 256) * 8;
  u16* ldsA_hi0 = &As_hi[0][0][0] + (size_t)(wid * 64) * 8;
  u16* ldsA_hi1 = &As_hi[0][0][0] + (size_t)(wid * 64 + 256) * 8;
  u16* ldsA_lo0 = &As_lo[0][0][0] + (size_t)(wid * 64) * 8;
  u16* ldsA_lo1 = &As_lo[0][0][0] + (size_t)(wid * 64 + 256) * 8;

  const int qr = tid >> 3, qc = tid & 7;
  const int kb = qc >> 1, off = (qc & 1) * 4;
  const float* Ag = Af ? (Af + (size_t)(row0 + qr) * lda + kbeg + qc * 4) : nullptr;

  f32x4 acc[4][4];
#pragma unroll
  for (int i = 0; i < 4; i++)
#pragma unroll
    for (int j = 0; j < 4; j++) acc[i][j] = (f32x4){0.f, 0.f, 0.f, 0.f};

  float4 ar[4];
#define LOADT(K0)                                                     \
  {                                                                   \
    _Pragma("unroll")                                                 \
    for (int i = 0; i < 4; i++)                                       \
      ar[i] = *(const float4*)(Ag + (size_t)(32 * i) * lda + (K0));   \
  }

  if constexpr (CONVA) LOADT(0);

  for (int kt = 0; kt < KT; kt++) {
    const int k0 = kt << 5;              // relative to kbeg
    const int kw = kbeg + k0;            // absolute (for W/A plane addrs)

    gll16(Whi + (size_t)(col0 + rA0) * K + kw + kA0 * 8, ldsW_hi0);
    gll16(Whi + (size_t)(col0 + rA1) * K + kw + kA1 * 8, ldsW_hi1);
    gll16(Wlo + (size_t)(col0 + rA0) * K + kw + kA0 * 8, ldsW_lo0);
    gll16(Wlo + (size_t)(col0 + rA1) * K + kw + kA1 * 8, ldsW_lo1);

    if constexpr (CONVA) {
#pragma unroll
      for (int i = 0; i < 4; i++) {
        const int row = qr + 32 * i;
        const float4 v = ar[i];
        const u16 h0 = bf16rn(v.x), h1 = bf16rn(v.y), h2 = bf16rn(v.z), h3 = bf16rn(v.w);
        const u16 l0 = bf16rn(v.x - bf16tof(h0)), l1 = bf16rn(v.y - bf16tof(h1));
        const u16 l2 = bf16rn(v.z - bf16tof(h2)), l3 = bf16rn(v.w - bf16tof(h3));
        *(uint2*)&As_hi[kb][row][off] = make_uint2(h0 | ((unsigned)h1 << 16), h2 | ((unsigned)h3 << 16));
        *(uint2*)&As_lo[kb][row][off] = make_uint2(l0 | ((unsigned)l1 << 16), l2 | ((unsigned)l3 << 16));
      }
      if (kt + 1 < KT) LOADT(k0 + 32);
    } else {
      gll16(Ahi + (size_t)(row0 + rA0) * lda + kw + kA0 * 8, ldsA_hi0);
      gll16(Ahi + (size_t)(row0 + rA1) * lda + kw + kA1 * 8, ldsA_hi1);
      gll16(Alo + (size_t)(row0 + rA0) * lda + kw + kA0 * 8, ldsA_lo0);
      gll16(Alo + (size_t)(row0 + rA1) * lda + kw + kA1 * 8, ldsA_lo1);
    }
    __syncthreads();

    short8 ah[4], al[4];
#pragma unroll
    for (int mi = 0; mi < 4; mi++) {
      ah[mi] = *(const short8*)&As_hi[lk][wy * 64 + mi * 16 + lr][0];
      al[mi] = *(const short8*)&As_lo[lk][wy * 64 + mi * 16 + lr][0];
    }
#pragma unroll
    for (int ni = 0; ni < 4; ni++) {
      const short8 bh = *(const short8*)&Ws_hi[lk][wx * 64 + ni * 16 + lr][0];
      const short8 bl = *(const short8*)&Ws_lo[lk][wx * 64 + ni * 16 + lr][0];
#pragma unroll
      for (int mi = 0; mi < 4; mi++) {
        acc[mi][ni] = __builtin_amdgcn_mfma_f32_16x16x32_bf16(ah[mi], bh, acc[mi][ni], 0, 0, 0);
        acc[mi][ni] = __builtin_amdgcn_mfma_f32_16x16x32_bf16(ah[mi], bl, acc[mi][ni], 0, 0, 0);
        acc[mi][ni] = __builtin_amdgcn_mfma_f32_16x16x32_bf16(al[mi], bh, acc[mi][ni], 0, 0, 0);
      }
    }
    __syncthreads();
  }
#undef LOADT

#pragma unroll
  for (int mi = 0; mi < 4; mi++)
#pragma unroll
    for (int ni = 0; ni < 4; ni++)
#pragma unroll
      for (int j = 0; j < 4; j++) {
        const int row = row0 + wy * 64 + mi * 16 + lk * 4 + j;
        const int col = col0 + wx * 64 + ni * 16 + lr;
        const float v = acc[mi][ni][j];
        if (EPI == 0) {
          C0[(size_t)row * N + col] = v;
        } else if (EPI == 1) {
          if (col < D_INNER) C0[(size_t)row * D_INNER + col] = v;
          else C1[(size_t)row * D_INNER + col - D_INNER] = v / (1.f + __expf(-v));
        } else if (EPI == 2) {
          const float t = v + bias[col];
          C0[(size_t)row * N + col] = (t > 20.f) ? t : log1pf(expf(t));
        } else {
          if (col < XP_N)
            C0[((size_t)ks * M + row) * XP_N + col] = v;
        }
      }
}

// sum XP_KS K-split partial slices -> out (float4-wide)
__global__ __launch_bounds__(256) void reduce_ksplit(
    const float* __restrict__ part, float* __restrict__ outp, int n4)
{
  const int i = blockIdx.x * 256 + threadIdx.x;
  if (i >= n4) return;
  f32x4 s = ((const f32x4*)part)[i];
#pragma unroll
  for (int k = 1; k < XP_KS; k++)
    s += ((const f32x4*)part)[i + (size_t)k * n4];
  ((f32x4*)outp)[i] = s;
}

// ---------------------------------------------------------------------------
// Causal depthwise conv1d (K=4) + bias + SiLU.  (B,L,D) d-contig.
// ---------------------------------------------------------------------------
__global__ __launch_bounds__(256) void conv_silu(
    const float* __restrict__ x, const float* __restrict__ w,
    const float* __restrict__ b, float* __restrict__ xs)
{
  const int idx = blockIdx.x * 256 + threadIdx.x;
  const int d = idx & (D_INNER - 1);
  const int bl = idx / D_INNER;
  const int l = bl & (SEQLEN - 1);
  float acc = b[d];
#pragma unroll
  for (int k = 0; k < 4; k++) {
    int ls = l + k - 3;
    if (ls >= 0) acc = fmaf(x[(size_t)(bl + k - 3) * D_INNER + d], w[d * 4 + k], acc);
  }
  xs[idx] = acc / (1.f + __expf(-acc));
}

// ---------------------------------------------------------------------------
// Chunked selective scan, lane-owns-channel (16 states in regs per lane).
// ---------------------------------------------------------------------------
__global__ __launch_bounds__(256) void scan_pass1(
    const float* __restrict__ dtb, const float* __restrict__ xs,
    const float* __restrict__ xdbl, const float* __restrict__ A_log,
    float* __restrict__ Pb, float* __restrict__ Sb)
{
  const int gid = blockIdx.x * 256 + threadIdx.x;
  const int d = gid & (D_INNER - 1);
  const int rest = gid >> 11;
  const int b = rest >> 5;
  const int chunk = rest & (NCHUNK - 1);

  float Av[16];
#pragma unroll
  for (int i = 0; i < 4; i++) {
    const f32x4 a4 = *(const f32x4*)(A_log + d * D_STATE + i * 4);
#pragma unroll
    for (int j = 0; j < 4; j++) Av[i * 4 + j] = -__expf(a4[j]);
  }

  float P[16], S[16];
#pragma unroll
  for (int n = 0; n < 16; n++) { P[n] = 1.f; S[n] = 0.f; }

  const int l0 = chunk * LCHUNK;
  const size_t base = (size_t)(b * SEQLEN + l0) * D_INNER + d;
  const float* pdt = dtb + base;
  const float* pxs = xs + base;
  const float* pB = xdbl + (size_t)(b * SEQLEN + l0) * 96 + 64;

#pragma unroll 2
  for (int l = 0; l < LCHUNK; l++) {
    const float dtv = *pdt; pdt += D_INNER;
    const float xv  = *pxs; pxs += D_INNER;
    f32x4 B4[4];
#pragma unroll
    for (int i = 0; i < 4; i++) B4[i] = *(const f32x4*)(pB + 4 * i);
    pB += 96;
    const float u = dtv * xv;
#pragma unroll
    for (int n = 0; n < 16; n++) {
      const float a = __expf(dtv * Av[n]);
      P[n] *= a;
      S[n] = fmaf(S[n], a, u * B4[n >> 2][n & 3]);
    }
  }

  const size_t ob = ((size_t)chunk * NCH + (size_t)b * D_INNER + d) * 16;
#pragma unroll
  for (int i = 0; i < 4; i++) {
    *(f32x4*)(Pb + ob + 4 * i) = (f32x4){P[4*i], P[4*i+1], P[4*i+2], P[4*i+3]};
    *(f32x4*)(Sb + ob + 4 * i) = (f32x4){S[4*i], S[4*i+1], S[4*i+2], S[4*i+3]};
  }
}

// Per (ch,n): exclusive scan over chunk transitions -> incoming states.
__global__ __launch_bounds__(256) void scan_pass2(
    const float* __restrict__ Pb, float* __restrict__ Sb)
{
  const int gid = blockIdx.x * 256 + threadIdx.x;   // = ch*16 + n
  float I = 0.f;
#pragma unroll
  for (int c = 0; c < NCHUNK; c++) {
    const size_t idx = (size_t)gid + (size_t)c * NCH * 16;
    const float P = Pb[idx];
    const float S = Sb[idx];
    Sb[idx] = I;
    I = fmaf(I, P, S);
  }
}

__global__ __launch_bounds__(256) void scan_pass3(
    const float* dtb, const float* __restrict__ xs,
    const float* __restrict__ gz, const float* __restrict__ xdbl,
    const float* __restrict__ A_log, const float* __restrict__ Dp,
    const float* __restrict__ Sb, float* y)
{
  const int gid = blockIdx.x * 256 + threadIdx.x;
  const int d = gid & (D_INNER - 1);
  const int rest = gid >> 11;
  const int b = rest >> 5;
  const int chunk = rest & (NCHUNK - 1);

  float Av[16];
#pragma unroll
  for (int i = 0; i < 4; i++) {
    const f32x4 a4 = *(const f32x4*)(A_log + d * D_STATE + i * 4);
#pragma unroll
    for (int j = 0; j < 4; j++) Av[i * 4 + j] = -__expf(a4[j]);
  }
  const float Dval = Dp[d];

  float S[16];
  const size_t sb = ((size_t)chunk * NCH + (size_t)b * D_INNER + d) * 16;
#pragma unroll
  for (int i = 0; i < 4; i++) {
    const f32x4 s4 = *(const f32x4*)(Sb + sb + 4 * i);
#pragma unroll
    for (int j = 0; j < 4; j++) S[i * 4 + j] = s4[j];
  }

  const int l0 = chunk * LCHUNK;
  const size_t base = (size_t)(b * SEQLEN + l0) * D_INNER + d;
  const float* pdt = dtb + base;
  const float* pxs = xs + base;
  const float* pg  = gz + base;
  const float* pB  = xdbl + (size_t)(b * SEQLEN + l0) * 96 + 64;
  float* py = y + base;

#pragma unroll 2
  for (int l = 0; l < LCHUNK; l++) {
    const float dtv = *pdt; pdt += D_INNER;
    const float xv  = *pxs; pxs += D_INNER;
    const float gv  = *pg;  pg += D_INNER;
    f32x4 B4[4], C4[4];
#pragma unroll
    for (int i = 0; i < 4; i++) B4[i] = *(const f32x4*)(pB + 4 * i);
#pragma unroll
    for (int i = 0; i < 4; i++) C4[i] = *(const f32x4*)(pB + 16 + 4 * i);
    pB += 96;

    const float u = dtv * xv;
    float yv = xv * Dval;
#pragma unroll
    for (int n = 0; n < 16; n++) {
      const float a = __expf(dtv * Av[n]);
      S[n] = fmaf(S[n], a, u * B4[n >> 2][n & 3]);
      yv = fmaf(S[n], C4[n >> 2][n & 3], yv);
    }
    *py = yv * gv;
    py += D_INNER;
  }
}

// ---------------------------------------------------------------------------
// Workspace (proven 220.9 MB budget):
//   xbuf(67.1) zbuf(67.1) xsbuf(67.1) xdbl(3.1) = 204.4 MB
//   + wxp/wdt planes after xdbl: 1.4 MB  => 205.8 MB
// Aliases: hid/win planes in xsbuf (dead at conv); wout planes in zbuf
// (split after pass3); Pb/Sb in d_out (dead before out_proj);
// x_proj K-split partials (50 MB) in xbuf during step 3 (x dead, dt not yet).
// ---------------------------------------------------------------------------
extern "C" void kernel_launch(void* const* d_in, const int* in_sizes, int n_in,
                              void* d_out, int out_size, void* d_ws, size_t ws_size,
                              hipStream_t stream)
{
  const float* hidden     = (const float*)d_in[0];
  const float* in_proj_w  = (const float*)d_in[1];
  const float* conv_w     = (const float*)d_in[2];
  const float* conv_b     = (const float*)d_in[3];
  const float* x_proj_w   = (const float*)d_in[4];
  const float* dt_proj_w  = (const float*)d_in[5];
  const float* dt_proj_b  = (const float*)d_in[6];
  const float* A_log      = (const float*)d_in[7];
  const float* Dparam     = (const float*)d_in[8];
  const float* out_proj_w = (const float*)d_in[9];
  float* out = (float*)d_out;

  const size_t NE = (size_t)NROWS * D_INNER;      // 16.78M floats
  float* xbuf  = (float*)d_ws;                    // x -> xp partials -> dt -> y
  float* zbuf  = xbuf + NE;                       // silu(z); later wout planes
  float* xsbuf = zbuf + NE;                       // early: hid+win planes
  float* xdbl  = xsbuf + NE;                      // NROWS*96

  // small persistent planes after xdbl (within proven budget)
  u16* wxphi = (u16*)(xdbl + (size_t)NROWS * 96); // 96*2048
  u16* wxplo = wxphi + (size_t)XP_N * D_INNER;
  u16* wdthi = wxplo + (size_t)XP_N * D_INNER;    // 2048*64
  u16* wdtlo = wdthi + (size_t)D_INNER * DT_RANK;

  // Pb/Sb live in d_out (2 * NCH*NCHUNK*16 = 8.39M floats = out_size)
  float* Pb = out;
  float* Sb = out + (size_t)NCH * NCHUNK * 16;

  // plane aliases
  u16* hidhi = (u16*)xsbuf;
  u16* hidlo = hidhi + (size_t)NROWS * D_MODEL;
  u16* winhi = hidlo + (size_t)NROWS * D_MODEL;
  u16* winlo = winhi + (size_t)2 * D_INNER * D_MODEL;
  u16* wouthi = (u16*)zbuf;
  u16* woutlo = wouthi + (size_t)D_MODEL * D_INNER;

  // 0) pre-split fp32 -> bf16 hi/lo planes
  {
    int n4 = (NROWS * D_MODEL) / 4;
    split_planes<<<(n4 + 255) / 256, 256, 0, stream>>>(hidden, hidhi, hidlo, n4);
    n4 = (2 * D_INNER * D_MODEL) / 4;
    split_planes<<<(n4 + 255) / 256, 256, 0, stream>>>(in_proj_w, winhi, winlo, n4);
    n4 = (XP_N * D_INNER) / 4;
    split_planes<<<(n4 + 255) / 256, 256, 0, stream>>>(x_proj_w, wxphi, wxplo, n4);
    n4 = (D_INNER * DT_RANK) / 4;
    split_planes<<<(n4 + 255) / 256, 256, 0, stream>>>(dt_proj_w, wdthi, wdtlo, n4);
  }

  // 1) in_proj (plane MFMA): -> x | silu(z)
  gemm_mfma2<1, 0><<<dim3((2 * D_INNER) / 128, NROWS / 128, 1), 256, 0, stream>>>(
      nullptr, hidhi, hidlo, winhi, winlo, xbuf, zbuf, nullptr,
      NROWS, 2 * D_INNER, D_MODEL, D_MODEL, 1);

  // 2) causal depthwise conv + SiLU (overwrites dead hid/win planes)
  conv_silu<<<(NROWS * D_INNER) / 256, 256, 0, stream>>>(xbuf, conv_w, conv_b, xsbuf);

  // 3) x_proj (split-K MFMA, partials into xbuf) -> reduce -> x_dbl
  gemm_mfma2<3, 1><<<dim3(1, NROWS / 128, XP_KS), 256, 0, stream>>>(
      xsbuf, nullptr, nullptr, wxphi, wxplo, xbuf, nullptr, nullptr,
      NROWS, XP_N, D_INNER, D_INNER, XP_KS);
  {
    const int n4 = (NROWS * XP_N) / 4;
    reduce_ksplit<<<(n4 + 255) / 256, 256, 0, stream>>>(xbuf, xdbl, n4);
  }

  // 4) dt_proj + softplus (MFMA) -> dt (into xbuf, partials dead)
  gemm_mfma2<2, 1><<<dim3(D_INNER / 128, NROWS / 128, 1), 256, 0, stream>>>(
      xdbl, nullptr, nullptr, wdthi, wdtlo, xbuf, nullptr, dt_proj_b,
      NROWS, D_INNER, DT_RANK, 96, 1);

  // 5) chunked selective scan (lane-owns-channel); y overwrites dt in xbuf
  scan_pass1<<<(NCH * NCHUNK) / 256, 256, 0, stream>>>(
      xbuf, xsbuf, xdbl, A_log, Pb, Sb);
  scan_pass2<<<(NCH * 16) / 256, 256, 0, stream>>>(Pb, Sb);
  scan_pass3<<<(NCH * NCHUNK) / 256, 256, 0, stream>>>(
      xbuf, xsbuf, zbuf, xdbl, A_log, Dparam, Sb, xbuf);

  // 5.5) split out_proj_w planes into zbuf (dead after pass3)
  {
    const int n4 = (D_MODEL * D_INNER) / 4;
    split_planes<<<(n4 + 255) / 256, 256, 0, stream>>>(out_proj_w, wouthi, woutlo, n4);
  }

  // 6) out_proj (A fp32-convert, W planes) -> out (overwrites Pb/Sb)
  gemm_mfma2<0, 1><<<dim3(D_MODEL / 128, NROWS / 128, 1), 256, 0, stream>>>(
      xbuf, nullptr, nullptr, wouthi, woutlo, out, nullptr, nullptr,
      NROWS, D_MODEL, D_INNER, D_INNER, 1);
}